// Round 9
// baseline (214.532 us; speedup 1.0000x reference)
//
#include <hip/hip_runtime.h>
#include <math.h>

typedef _Float16 h16;

#define DEV static __device__ __forceinline__

constexpr int B_ = 8, C_ = 128, L_ = 4096, OUT_ = 128;
constexpr int NCH = 4, DM = 32, DS = 16, DI = 64;
constexpr int NI = 32;            // B_*NCH instances
constexpr int NSEG = 128;         // scan segments
constexpr int SL = L_ / NSEG;     // 32 steps per segment

DEV float sigmoidf_(float x) { return 1.f / (1.f + __expf(-x)); }
DEV float siluf_(float x) { return x * sigmoidf_(x); }
DEV float softplusf_(float x) { return (x > 20.f) ? x : __logf(1.f + __expf(x)); }

template <int CTRL>
DEV float dpp_add_(float x) {
  int v = __builtin_amdgcn_update_dpp(0, __float_as_int(x), CTRL, 0xf, 0xf, false);
  return x + __int_as_float(v);
}

typedef __attribute__((ext_vector_type(8))) _Float16 f16x8;
typedef __attribute__((ext_vector_type(4))) _Float16 f16x4;
typedef __attribute__((ext_vector_type(4))) float f32x4;

// log-depth powers: out[s] = E^(s+1)
DEV void powladder_(float E, float* out) {
  float E2 = E * E;
  float E4 = E2 * E2;
  float E8 = E4 * E4;
  float E3 = E2 * E;
  out[0] = E;       out[1] = E2;      out[2] = E3;      out[3] = E4;
  out[4] = E4 * E;  out[5] = E4 * E2; out[6] = E4 * E3; out[7] = E8;
  out[8] = E8 * E;  out[9] = E8 * E2; out[10] = E8 * E3; out[11] = E8 * E4;
  out[12] = E8 * out[4]; out[13] = E8 * out[5]; out[14] = E8 * out[6];
  out[15] = E8 * E8;
}

// 8-deep ladder: out[j] = E^(j+1)
DEV void powladder8_(float E, float* out) {
  float E2 = E * E, E3 = E2 * E, E4 = E2 * E2;
  out[0] = E; out[1] = E2; out[2] = E3; out[3] = E4;
  out[4] = E4 * E; out[5] = E4 * E2; out[6] = E4 * E3; out[7] = E4 * E4;
}

// ---------------- K0: one-shot weight convert to h16 + workspace zero --------
__global__ __launch_bounds__(256) void k0_wcvt(const float* __restrict__ in_W,
                                               const float* __restrict__ xproj_W,
                                               h16* __restrict__ WH,
                                               float* __restrict__ Zp) {
  int tid = blockIdx.x * 256 + threadIdx.x;
  if (tid < 3072) Zp[tid] = 0.f;
  if (tid < 4096) {
    WH[tid] = (h16)in_W[tid];
  } else {
    int j = tid - 4096;
    int r = j >> 6;
    WH[tid] = (r < 34) ? (h16)xproj_W[r * 64 + (j & 63)] : (h16)0.f;
  }
}

// ---------------- K1: LayerNorm1, 32-token tiles (1024 blocks, 4+/CU) --------
__global__ __launch_bounds__(256) void k1_ln(const float* __restrict__ x,
                                             const float* __restrict__ gn,
                                             const float* __restrict__ bn,
                                             h16* __restrict__ XNH,
                                             float* __restrict__ SUMXN) {
  int bid = blockIdx.x;
  int b = bid >> 7, tile = bid & 127;
  int t0 = tile * 32;
  int tid = threadIdx.x;
  __shared__ float xT[128][33];
  __shared__ float gnS[128], bnS[128];
  __shared__ float red[256];
  if (tid < 128) { gnS[tid] = gn[tid]; bnS[tid] = bn[tid]; }
  for (int k = tid; k < 4096; k += 256) {
    int c = k >> 5, tt = k & 31;
    xT[c][tt] = x[((size_t)(b * C_ + c)) * L_ + t0 + tt];
  }
  __syncthreads();
  if (tid < 128) {
    int tok = tid >> 2, q = tid & 3;
    float s = 0.f, qq = 0.f;
#pragma unroll
    for (int j = 0; j < 32; ++j) {
      float v = xT[q + 4 * j][tok];
      s += v; qq += v * v;
    }
    s = dpp_add_<0xB1>(s); qq = dpp_add_<0xB1>(qq);
    s = dpp_add_<0x4E>(s); qq = dpp_add_<0x4E>(qq);
    float m = s * (1.f / 128.f);
    float var = qq * (1.f / 128.f) - m * m;
    float rs = rsqrtf(var + 1e-5f);
#pragma unroll
    for (int j = 0; j < 32; ++j) {
      int c = q + 4 * j;
      float v = xT[c][tok];
      xT[c][tok] = (v - m) * rs * gnS[c] + bnS[c];
    }
  }
  __syncthreads();
  float acc = 0.f;
  for (int k = tid; k < 4096; k += 256) {
    int tt = k >> 7, c = k & 127;
    acc += xT[c][tt];
  }
  // h16 write (coalesced 16B stores)
  for (int k = tid; k < 512; k += 256) {
    int tt = k >> 4, c8 = (k & 15) * 8;
    f16x8 hv;
#pragma unroll
    for (int j = 0; j < 8; ++j) hv[j] = (_Float16)xT[c8 + j][tt];
    *(f16x8*)&XNH[((size_t)(b * L_ + t0 + tt)) * C_ + c8] = hv;
  }
  red[tid] = acc;
  __syncthreads();
  if (tid < 128) atomicAdd(&SUMXN[b * C_ + tid], red[tid] + red[tid + 128]);
}

// ---------------- K2: in-proj + conv + silu + x-proj + dt + z + LOCAL SCAN ----
__global__ __launch_bounds__(256) void k2_prep(
    const h16* __restrict__ WH, const float* __restrict__ conv_W,
    const float* __restrict__ conv_b, const float* __restrict__ dt_W,
    const float* __restrict__ dt_b, const float* __restrict__ A_log,
    const h16* __restrict__ XNH, h16* __restrict__ SX2, h16* __restrict__ SDT2,
    h16* __restrict__ SB2, h16* __restrict__ SC2, h16* __restrict__ SZ2,
    float* __restrict__ Pp, float* __restrict__ Qp) {
  int bid = blockIdx.x;
  int i = bid >> 6, tile = bid & 63;
  int b = i >> 2, ch = i & 3;
  int t0 = tile * 64;
  int tid = threadIdx.x;
  int w = __builtin_amdgcn_readfirstlane(tid >> 6);
  int lane = tid & 63;

  __shared__ __attribute__((aligned(16))) union {
    _Float16 uH[80][40];   // rows 0..66 = tokens t0-3..t0+63; 67..79 zero
    float xdS[64][36];     // x-proj output, row=token, col=o (34 used)
    _Float16 zL[64][72];   // silu(z) bounce
  } U;
  __shared__ __attribute__((aligned(16))) _Float16 preH[68][68];  // in-proj out; later dtL
  __shared__ __attribute__((aligned(16))) _Float16 xH[64][72];    // conv+silu out
  __shared__ float convWS[64][4];
  __shared__ float dtWS[64][2];
  __shared__ float dtbS[64], cbS[64];

  convWS[tid >> 2][tid & 3] = conv_W[tid];
  if (tid < 128) dtWS[tid >> 1][tid & 1] = dt_W[tid];
  if (tid < 64) { dtbS[tid] = dt_b[tid]; cbS[tid] = conv_b[tid]; }
  // u from XNH (16B vector loads)
  const h16* xnh = XNH + (size_t)b * L_ * C_ + ch * DM;
  for (int k = tid; k < 320; k += 256) {
    int r = k >> 2, c8 = (k & 3) * 8;
    int tg = t0 - 3 + r;
    f16x8 v = {0, 0, 0, 0, 0, 0, 0, 0};
    if (r < 67 && tg >= 0) v = *(const f16x8*)&xnh[(size_t)tg * C_ + c8];
    *(f16x8*)&U.uH[r][c8] = v;
  }
  __syncthreads();

  int rsel = lane & 15, ksel = (lane >> 4) * 8;
  // in-proj MFMA: wave w owns N-tile nt=w; B-frag direct from WH (L2-hot)
  {
    int nt = w;
    f16x8 bf = *(const f16x8*)&WH[(size_t)(nt * 16 + rsel) * 32 + ksel];
    int row0q = (lane >> 4) << 2;
    int col = nt * 16 + rsel;
#pragma unroll
    for (int mt = 0; mt < 5; ++mt) {
      f16x8 af = *(const f16x8*)&U.uH[mt * 16 + rsel][ksel];
      f32x4 acc = {0.f, 0.f, 0.f, 0.f};
      acc = __builtin_amdgcn_mfma_f32_16x16x32_f16(af, bf, acc, 0, 0, 0);
      int row0 = mt * 16 + row0q;
#pragma unroll
      for (int r = 0; r < 4; ++r) {
        int row = row0 + r;
        if (row < 67) preH[row][col] = (_Float16)acc[r];
      }
    }
  }
  // z-gate MFMA (transposed): D[zd][token]; A-frags direct from WH
  f32x4 zacc[4];
  {
    f16x8 bf = *(const f16x8*)&U.uH[3 + w * 16 + rsel][ksel];
#pragma unroll
    for (int mt = 0; mt < 4; ++mt) {
      f16x8 af = *(const f16x8*)&WH[(size_t)(64 + mt * 16 + rsel) * 32 + ksel];
      f32x4 acc = {0.f, 0.f, 0.f, 0.f};
      zacc[mt] = __builtin_amdgcn_mfma_f32_16x16x32_f16(af, bf, acc, 0, 0, 0);
    }
  }
  __syncthreads();

  // causal depthwise conv + silu; write xH + SX2 inline
  h16* SXp = SX2 + ((size_t)i * L_ + t0) * DI;
  for (int k = tid; k < 4096; k += 256) {
    int r = k >> 6, d = k & 63;
    float v = cbS[d];
#pragma unroll
    for (int j = 0; j < 4; ++j) v = fmaf(convWS[d][j], (float)preH[r + j][d], v);
    v = siluf_(v);
    xH[r][d] = (_Float16)v;
    SXp[(size_t)r * DI + d] = (h16)v;
  }
  __syncthreads();

  // x-proj MFMA: wave w owns M-tile mt=w; B-frags direct from WH
  {
    int mt = w;
    f16x8 a0 = *(const f16x8*)&xH[mt * 16 + rsel][ksel];
    f16x8 a1 = *(const f16x8*)&xH[mt * 16 + rsel][32 + ksel];
    int row0 = mt * 16 + ((lane >> 4) << 2);
#pragma unroll
    for (int nt = 0; nt < 3; ++nt) {
      const h16* wp = WH + 4096 + (size_t)(nt * 16 + rsel) * 64;
      f16x8 b0 = *(const f16x8*)&wp[ksel];
      f16x8 b1 = *(const f16x8*)&wp[32 + ksel];
      f32x4 acc = {0.f, 0.f, 0.f, 0.f};
      acc = __builtin_amdgcn_mfma_f32_16x16x32_f16(a0, b0, acc, 0, 0, 0);
      acc = __builtin_amdgcn_mfma_f32_16x16x32_f16(a1, b1, acc, 0, 0, 0);
      int col = nt * 16 + rsel;
      if (col < 34) {
#pragma unroll
        for (int r = 0; r < 4; ++r) U.xdS[row0 + r][col] = acc[r];
      }
    }
  }
  __syncthreads();

  // dt -> LDS (reuse dead preH, stride 68) + SDT2; B/C writeout
  h16* dtL = (h16*)&preH[0][0];
  h16* SDTp = SDT2 + ((size_t)i * L_ + t0) * DI;
  for (int k = tid; k < 4096; k += 256) {
    int d = k & 63, r = k >> 6;
    float raw = fmaf(U.xdS[r][0], dtWS[d][0], fmaf(U.xdS[r][1], dtWS[d][1], dtbS[d]));
    float dtv = softplusf_(raw);
    dtL[r * 68 + d] = (_Float16)dtv;
    SDTp[(size_t)r * DI + d] = (h16)dtv;
  }
  h16* SBp = SB2 + ((size_t)i * L_ + t0) * DS;
  h16* SCp = SC2 + ((size_t)i * L_ + t0) * DS;
  for (int k = tid; k < 1024; k += 256) {
    int s = k & 15, r = k >> 4;
    SBp[(size_t)r * DS + s] = (h16)U.xdS[r][2 + s];
    SCp[(size_t)r * DS + s] = (h16)U.xdS[r][18 + s];
  }
  __syncthreads();

  // ---- fused local scan: wave w -> seg=w>>1, shalf=w&1, d=lane
  {
    int seg = w >> 1, shalf = w & 1;
    int s0 = shalf * 8;
    float Av[16];
#pragma unroll
    for (int s = 0; s < 16; ++s) Av[s] = -__expf(A_log[lane * 16 + s]);
    float A0 = Av[0];
    bool okf = true;
#pragma unroll
    for (int s = 0; s < 16; ++s)
      okf &= fabsf(Av[s] - (float)(s + 1) * A0) <= 1e-4f * fabsf(Av[s]);
    int fastp = __all(okf ? 1 : 0);
    float h[8];
#pragma unroll
    for (int j = 0; j < 8; ++j) h[j] = 0.f;
    float sdt = 0.f;
    int rowbase = seg * SL;
    for (int t = 0; t < SL; ++t) {
      int row = rowbase + t;
      float dt = (float)dtL[row * 68 + lane];
      float xv = (float)xH[row][lane];
      float dtx = dt * xv;
      float dA[8];
      if (fastp) {
        powladder8_(__expf(A0 * dt), dA);
        if (shalf) {
          float E8 = dA[7];
#pragma unroll
          for (int j = 0; j < 8; ++j) dA[j] *= E8;
        }
      } else {
#pragma unroll
        for (int j = 0; j < 8; ++j) dA[j] = __expf(Av[s0 + j] * dt);
      }
      const float* brow = &U.xdS[row][2 + s0];
#pragma unroll
      for (int j = 0; j < 8; ++j) h[j] = fmaf(dA[j], h[j], dtx * brow[j]);
      sdt += dt;
    }
    float P[8];
    if (fastp) {
      powladder8_(__expf(A0 * sdt), P);
      if (shalf) {
        float E8 = P[7];
#pragma unroll
        for (int j = 0; j < 8; ++j) P[j] *= E8;
      }
    } else {
#pragma unroll
      for (int j = 0; j < 8; ++j) P[j] = __expf(Av[s0 + j] * sdt);
    }
    int segg = tile * 2 + seg;
    // seg-major layout: [i][seg][d][s]
    size_t base = (((size_t)i * NSEG + segg) * DI + lane) * DS + s0;
    *(float4*)(Pp + base) = *(float4*)&P[0];
    *(float4*)(Pp + base + 4) = *(float4*)&P[4];
    *(float4*)(Qp + base) = *(float4*)&h[0];
    *(float4*)(Qp + base + 4) = *(float4*)&h[4];
  }
  __syncthreads();   // xdS fully consumed; reuse union as zL

  // z writeout: pack 4 consecutive zd per lane into LDS, then coalesced global
  {
    int tok = w * 16 + rsel;
    int zq = (lane >> 4) << 2;
#pragma unroll
    for (int mt = 0; mt < 4; ++mt) {
      f16x4 pk;
#pragma unroll
      for (int r = 0; r < 4; ++r) pk[r] = (_Float16)siluf_(zacc[mt][r]);
      *(f16x4*)&U.zL[tok][mt * 16 + zq] = pk;
    }
  }
  __syncthreads();
  h16* SZp = SZ2 + ((size_t)i * L_ + t0) * DI;
  for (int k = tid; k < 512; k += 256) {
    int r = k >> 3, dblk = (k & 7) * 8;
    f16x8 v = *(const f16x8*)&U.zL[r][dblk];
    *(f16x8*)&SZp[(size_t)r * DI + dblk] = v;
  }
}

// ---------------- K3b: inter-segment scan (512 blocks x 64 thr: all CUs) ------
__global__ __launch_bounds__(64) void k3b_comb(float* __restrict__ Pp,
                                               const float* __restrict__ Qp) {
  int g = blockIdx.x * 64 + threadIdx.x;  // 32768 = NI*DI*DS
  int ds = g & 1023;       // d*16+s within instance
  int i = g >> 10;
  size_t base = (size_t)i * NSEG * DI * DS + ds;
  constexpr int SST = DI * DS;   // 1024 floats per seg
  float H = 0.f;
  for (int sb = 0; sb < NSEG; sb += 16) {
    float Pv[16], Qv[16];
#pragma unroll
    for (int j = 0; j < 16; ++j) {
      size_t a = base + (size_t)(sb + j) * SST;
      Pv[j] = Pp[a];
      Qv[j] = Qp[a];
    }
#pragma unroll
    for (int j = 0; j < 16; ++j) {
      size_t a = base + (size_t)(sb + j) * SST;
      Pp[a] = H;
      H = fmaf(Pv[j], H, Qv[j]);
    }
  }
}

// ---------------- K3c: final scan, fused with D-term/z-gate-mult/token-sums ----
__global__ __launch_bounds__(256) void k3c_scan(
    const float* __restrict__ A_log, const h16* __restrict__ SDT2,
    const h16* __restrict__ SX2, const h16* __restrict__ SB2,
    const h16* __restrict__ SC2, const h16* __restrict__ SZ2,
    const float* __restrict__ D_p, const float* __restrict__ H0p,
    h16* __restrict__ YS2, float* __restrict__ SUMYF) {
  int bid = blockIdx.x;             // i*32 + sg
  int i = bid >> 5, sg = bid & 31;
  int tid = threadIdx.x;
  int w = tid >> 6, lane = tid & 63;
  int seg = sg * 4 + w;
  int t0 = seg * SL;
  __shared__ float rowS[4][SL][36];   // [w][t][ B16 | C16 ] + pad
  {
    int tk = lane & 31, hf = lane >> 5;
    const h16* p = (hf ? SC2 : SB2) + ((size_t)i * L_ + t0 + tk) * DS;
    float4 r0 = *(const float4*)p;
    float4 r1 = *(const float4*)(p + 8);
    const h16* hp0 = (const h16*)&r0;
    const h16* hp1 = (const h16*)&r1;
#pragma unroll
    for (int s = 0; s < 8; ++s) {
      rowS[w][tk][hf * 16 + s] = (float)hp0[s];
      rowS[w][tk][hf * 16 + 8 + s] = (float)hp1[s];
    }
  }
  __syncthreads();
  float Av[16];
#pragma unroll
  for (int s = 0; s < 16; ++s) Av[s] = -__expf(A_log[lane * 16 + s]);
  float A0 = Av[0];
  bool okf = true;
#pragma unroll
  for (int s = 0; s < 16; ++s) okf &= fabsf(Av[s] - (float)(s + 1) * A0) <= 1e-4f * fabsf(Av[s]);
  int fastp = __all(okf ? 1 : 0);
  float Dp = D_p[lane];
  float h[16];
  {
    size_t base = (((size_t)i * NSEG + seg) * DI + lane) * DS;
#pragma unroll
    for (int j = 0; j < 4; ++j) *(float4*)&h[4 * j] = *(const float4*)(H0p + base + 4 * j);
  }
  const h16* pdt = SDT2 + ((size_t)i * L_ + t0) * DI + lane;
  const h16* pxx = SX2 + ((size_t)i * L_ + t0) * DI + lane;
  const h16* pzz = SZ2 + ((size_t)i * L_ + t0) * DI + lane;
  h16* pys = YS2 + ((size_t)i * L_ + t0) * DI + lane;
  float dtc = (float)pdt[0], xvc = (float)pxx[0], zvc = (float)pzz[0];
  float sum = 0.f;
  for (int t = 0; t < SL; ++t) {
    float dt = dtc, xv = xvc, zv = zvc;
    if (t < SL - 1) {
      dtc = (float)pdt[(t + 1) * DI];
      xvc = (float)pxx[(t + 1) * DI];
      zvc = (float)pzz[(t + 1) * DI];
    }
    const float* row = &rowS[w][t][0];
    float Bv[16], Cv[16];
#pragma unroll
    for (int j = 0; j < 4; ++j) {
      *(float4*)&Bv[4 * j] = *(const float4*)(row + 4 * j);
      *(float4*)&Cv[4 * j] = *(const float4*)(row + 16 + 4 * j);
    }
    float dtx = dt * xv;
    float dA[16];
    if (fastp) {
      powladder_(__expf(A0 * dt), dA);
    } else {
#pragma unroll
      for (int s = 0; s < 16; ++s) dA[s] = __expf(Av[s] * dt);
    }
    float y0 = 0.f, y1 = 0.f, y2 = 0.f, y3 = 0.f;
#pragma unroll
    for (int s = 0; s < 16; s += 4) {
      h[s] = fmaf(dA[s], h[s], dtx * Bv[s]);       y0 = fmaf(h[s], Cv[s], y0);
      h[s + 1] = fmaf(dA[s + 1], h[s + 1], dtx * Bv[s + 1]); y1 = fmaf(h[s + 1], Cv[s + 1], y1);
      h[s + 2] = fmaf(dA[s + 2], h[s + 2], dtx * Bv[s + 2]); y2 = fmaf(h[s + 2], Cv[s + 2], y2);
      h[s + 3] = fmaf(dA[s + 3], h[s + 3], dtx * Bv[s + 3]); y3 = fmaf(h[s + 3], Cv[s + 3], y3);
    }
    float y = (y0 + y1) + (y2 + y3);
    float yf = fmaf(xv, Dp, y) * zv;
    pys[(size_t)t * DI] = (h16)yf;
    sum += yf;
  }
  atomicAdd(&SUMYF[i * DI + lane], sum);
}

// ---------------- K56: gates + gated combine + LN2 + proj, 32-token tiles -----
// 1024 blocks, LDS ~28.6KB -> 4/CU.
__global__ __launch_bounds__(256) void k56_comb_proj(
    const float* __restrict__ out_W, const float* __restrict__ skip_p,
    const float* __restrict__ se_W1, const float* __restrict__ se_W2,
    const float* __restrict__ SUMYF, const float* __restrict__ SUMXN,
    const h16* __restrict__ YS2, const float* __restrict__ gn,
    const float* __restrict__ bn, const float* __restrict__ proj_W,
    const float* __restrict__ proj_b, const h16* __restrict__ XNH,
    float* __restrict__ out) {
  int bid = blockIdx.x;
  int b = bid >> 7, tile = bid & 127;
  int t0 = tile * 32;
  int tid = threadIdx.x;
  int w = __builtin_amdgcn_readfirstlane(tid >> 6);
  int lane = tid & 63;
  __shared__ __attribute__((aligned(16))) union {
    float xmS[32][132];
    _Float16 projH[64][136];   // one 64-row half of proj_W per pass
  } U;
  __shared__ __attribute__((aligned(16))) union {
    struct {
      _Float16 yH[32][72];
      _Float16 owH[32][72];
    } pre;
    _Float16 xmH[32][136];
  } V;
  __shared__ float gAll[4][64];
  __shared__ float gnS[128], bnS[128];
  float* catS = (float*)&V.pre.yH[0][0];   // 4*64 floats
  float* seL = catS + 256;                 // 8 floats

  if (tid < 128) { gnS[tid] = gn[tid]; bnS[tid] = bn[tid]; }
  for (int k = tid; k < 2048; k += 256) V.pre.owH[k >> 6][k & 63] = (_Float16)out_W[k];
  // stage xm from XNH (h16 -> f32)
  const h16* xmh = XNH + (size_t)b * L_ * C_;
  for (int k = tid; k < 512; k += 256) {
    int tt = k >> 4, c8 = (k & 15) * 8;
    f16x8 hv = *(const f16x8*)&xmh[(size_t)(t0 + tt) * C_ + c8];
#pragma unroll
    for (int j = 0; j < 8; ++j) U.xmS[tt][c8 + j] = (float)hv[j];
  }
  // ---- gates (folded k4): phase A -> catS
  {
    int ch = tid >> 6, j = tid & 63;
    float invL = 1.f / (float)L_;
    if (j < 32) {
      const float* sy = SUMYF + (b * 4 + ch) * DI;
      const float* ow = out_W + j * 64;
      float acc = 0.f;
#pragma unroll
      for (int dd = 0; dd < 64; ++dd) acc = fmaf(sy[dd], ow[dd], acc);
      catS[ch * 64 + j] = acc * invL;
    } else {
      catS[ch * 64 + j] = skip_p[0] * SUMXN[b * C_ + ch * DM + (j - 32)] * invL;
    }
  }
  __syncthreads();
  if (tid < 8) {
    int ch = tid >> 1, r = tid & 1;
    float acc = 0.f;
#pragma unroll
    for (int k = 0; k < 64; ++k) acc = fmaf(catS[ch * 64 + k], se_W1[r * 64 + k], acc);
    seL[tid] = fmaxf(acc, 0.f);
  }
  __syncthreads();
  {
    int ch = tid >> 6, j = tid & 63;
    gAll[ch][j] = sigmoidf_(fmaf(seL[ch * 2], se_W2[j * 2], seL[ch * 2 + 1] * se_W2[j * 2 + 1]));
  }
  __syncthreads();   // gates done; yH region reusable

  int rsel = lane & 15, ksel = (lane >> 4) * 8;
  float skip = skip_p[0];
  int mt = w & 1, ntg = w >> 1;
  // per-channel gated combine: M=32, N=32; wave w -> (mt, nt=ntg)
  for (int ch = 0; ch < 4; ++ch) {
    const h16* py = YS2 + ((size_t)(b * 4 + ch) * L_ + t0) * DI;
    for (int k = tid; k < 256; k += 256) {
      int tt = k >> 3, dblk = (k & 7) * 8;
      *(f16x8*)&V.pre.yH[tt][dblk] = *(const f16x8*)&py[(size_t)tt * DI + dblk];
    }
    __syncthreads();
    f16x8 a0 = *(const f16x8*)&V.pre.yH[mt * 16 + rsel][ksel];
    f16x8 a1 = *(const f16x8*)&V.pre.yH[mt * 16 + rsel][32 + ksel];
    int row0 = mt * 16 + ((lane >> 4) << 2);
    {
      int nt = ntg;
      f16x8 b0 = *(const f16x8*)&V.pre.owH[nt * 16 + rsel][ksel];
      f16x8 b1 = *(const f16x8*)&V.pre.owH[nt * 16 + rsel][32 + ksel];
      f32x4 acc = {0.f, 0.f, 0.f, 0.f};
      acc = __builtin_amdgcn_mfma_f32_16x16x32_f16(a0, b0, acc, 0, 0, 0);
      acc = __builtin_amdgcn_mfma_f32_16x16x32_f16(a1, b1, acc, 0, 0, 0);
      int o = nt * 16 + rsel;
      float g1 = gAll[ch][o], g2s = gAll[ch][32 + o] * skip;
      int cc = ch * 32 + o;
#pragma unroll
      for (int r = 0; r < 4; ++r) {
        int tok = row0 + r;
        U.xmS[tok][cc] = g1 * acc[r] + g2s * U.xmS[tok][cc];
      }
    }
    __syncthreads();
  }

  // LN2 over xm rows (32 tokens, 4 threads each)
  if (tid < 128) {
    int tok = tid >> 2, q = tid & 3;
    float s = 0.f, qq = 0.f;
#pragma unroll
    for (int j = 0; j < 32; ++j) {
      float v = U.xmS[tok][4 * j + q];
      s += v; qq += v * v;
    }
    s = dpp_add_<0xB1>(s); qq = dpp_add_<0xB1>(qq);
    s = dpp_add_<0x4E>(s); qq = dpp_add_<0x4E>(qq);
    float m = s * (1.f / 128.f);
    float var = qq * (1.f / 128.f) - m * m;
    float rs = rsqrtf(var + 1e-5f);
#pragma unroll
    for (int j = 0; j < 32; ++j) {
      int c = 4 * j + q;
      float v = U.xmS[tok][c];
      U.xmS[tok][c] = (v - m) * rs * gnS[c] + bnS[c];
    }
  }
  __syncthreads();
  // convert LN output to h16 (xmH overlays dead yH/owH)
  for (int k = tid; k < 512; k += 256) {
    int tt = k >> 4, cblk = (k & 15) * 8;
    float4 v0 = *(const float4*)&U.xmS[tt][cblk];
    float4 v1 = *(const float4*)&U.xmS[tt][cblk + 4];
    f16x8 hv;
    hv[0] = (_Float16)v0.x; hv[1] = (_Float16)v0.y;
    hv[2] = (_Float16)v0.z; hv[3] = (_Float16)v0.w;
    hv[4] = (_Float16)v1.x; hv[5] = (_Float16)v1.y;
    hv[6] = (_Float16)v1.z; hv[7] = (_Float16)v1.w;
    *(f16x8*)&V.xmH[tt][cblk] = hv;
  }
  __syncthreads();
  // proj MFMA: M=32 (mt=w&1), per half 4 nt-tiles, wave ntg covers 2
  f16x8 af[4];
#pragma unroll
  for (int kc = 0; kc < 4; ++kc)
    af[kc] = *(const f16x8*)&V.xmH[mt * 16 + rsel][kc * 32 + ksel];
  int row0 = mt * 16 + ((lane >> 4) << 2);
#pragma unroll
  for (int half = 0; half < 2; ++half) {
    for (int k = tid; k < 1024; k += 256) {
      int o = k >> 4, cblk = (k & 15) * 8;
      const float* wp = proj_W + (half * 64 + o) * 128 + cblk;
      float4 v0 = *(const float4*)wp;
      float4 v1 = *(const float4*)(wp + 4);
      f16x8 hv;
      hv[0] = (_Float16)v0.x; hv[1] = (_Float16)v0.y;
      hv[2] = (_Float16)v0.z; hv[3] = (_Float16)v0.w;
      hv[4] = (_Float16)v1.x; hv[5] = (_Float16)v1.y;
      hv[6] = (_Float16)v1.z; hv[7] = (_Float16)v1.w;
      *(f16x8*)&U.projH[o][cblk] = hv;
    }
    __syncthreads();
#pragma unroll
    for (int nt = 0; nt < 2; ++nt) {
      int ol = (ntg * 2 + nt) * 16 + rsel;
      int o = half * 64 + ol;
      float pb = proj_b[o];
      f32x4 acc = {pb, pb, pb, pb};
#pragma unroll
      for (int kc = 0; kc < 4; ++kc) {
        f16x8 bf = *(const f16x8*)&U.projH[ol][kc * 32 + ksel];
        acc = __builtin_amdgcn_mfma_f32_16x16x32_f16(af[kc], bf, acc, 0, 0, 0);
      }
      *(float4*)&out[((size_t)(b * OUT_ + o)) * L_ + t0 + row0] =
          make_float4(acc[0], acc[1], acc[2], acc[3]);
    }
    __syncthreads();
  }
}

extern "C" void kernel_launch(void* const* d_in, const int* in_sizes, int n_in,
                              void* d_out, int out_size, void* d_ws, size_t ws_size,
                              hipStream_t stream) {
  const float* x = (const float*)d_in[0];
  const float* norm_g = (const float*)d_in[1];
  const float* norm_b = (const float*)d_in[2];
  const float* proj_W = (const float*)d_in[3];
  const float* proj_b = (const float*)d_in[4];
  const float* skip = (const float*)d_in[5];
  const float* se_W1 = (const float*)d_in[6];
  const float* se_W2 = (const float*)d_in[7];
  const float* in_W = (const float*)d_in[8];
  const float* conv_W = (const float*)d_in[9];
  const float* conv_b = (const float*)d_in[10];
  const float* xproj_W = (const float*)d_in[11];
  const float* dt_W = (const float*)d_in[12];
  const float* dt_b = (const float*)d_in[13];
  const float* A_log = (const float*)d_in[14];
  const float* D_p = (const float*)d_in[15];
  const float* out_W = (const float*)d_in[16];
  float* out = (float*)d_out;

  // workspace (~120 MiB)
  float* SUMYF = (float*)d_ws;                      // NI*DI
  float* SUMXN = SUMYF + NI * DI;                   // B*C
  float* Pp = SUMXN + B_ * C_;                      // NI*NSEG*DI*DS f32 (seg-major)
  float* Qp = Pp + (size_t)NI * DI * NSEG * DS;
  h16* YS2 = (h16*)(Qp + (size_t)NI * DI * NSEG * DS);  // NI*L*DI h16
  h16* SX2 = YS2 + (size_t)NI * L_ * DI;
  h16* SDT2 = SX2 + (size_t)NI * L_ * DI;
  h16* SB2 = SDT2 + (size_t)NI * L_ * DI;           // NI*L*DS h16
  h16* SC2 = SB2 + (size_t)NI * L_ * DS;
  h16* SZ2 = SC2 + (size_t)NI * L_ * DS;            // NI*L*DI h16 (silu(z))
  h16* XNH = SZ2 + (size_t)NI * L_ * DI;            // B*L*C h16
  h16* WH = XNH + (size_t)B_ * L_ * C_;             // 7168 h16

  k0_wcvt<<<28, 256, 0, stream>>>(in_W, xproj_W, WH, SUMYF);
  k1_ln<<<B_ * 128, 256, 0, stream>>>(x, norm_g, norm_b, XNH, SUMXN);
  k2_prep<<<NI * 64, 256, 0, stream>>>(WH, conv_W, conv_b, dt_W, dt_b, A_log,
                                       XNH, SX2, SDT2, SB2, SC2, SZ2, Pp, Qp);
  k3b_comb<<<512, 64, 0, stream>>>(Pp, Qp);
  k3c_scan<<<NI * 32, 256, 0, stream>>>(A_log, SDT2, SX2, SB2, SC2, SZ2, D_p,
                                        Pp, YS2, SUMYF);
  k56_comb_proj<<<B_ * 128, 256, 0, stream>>>(out_W, skip, se_W1, se_W2, SUMYF,
                                              SUMXN, YS2, norm_g, norm_b, proj_W,
                                              proj_b, XNH, out);
}

// Round 10
// 210.257 us; speedup vs baseline: 1.0203x; 1.0203x over previous
//
#include <hip/hip_runtime.h>
#include <math.h>

typedef _Float16 h16;

#define DEV static __device__ __forceinline__

constexpr int B_ = 8, C_ = 128, L_ = 4096, OUT_ = 128;
constexpr int NCH = 4, DM = 32, DS = 16, DI = 64;
constexpr int NI = 32;            // B_*NCH instances
constexpr int NSEG = 128;         // scan segments
constexpr int SL = L_ / NSEG;     // 32 steps per segment

DEV float sigmoidf_(float x) { return 1.f / (1.f + __expf(-x)); }
DEV float siluf_(float x) { return x * sigmoidf_(x); }
DEV float softplusf_(float x) { return (x > 20.f) ? x : __logf(1.f + __expf(x)); }

template <int CTRL>
DEV float dpp_add_(float x) {
  int v = __builtin_amdgcn_update_dpp(0, __float_as_int(x), CTRL, 0xf, 0xf, false);
  return x + __int_as_float(v);
}

typedef __attribute__((ext_vector_type(8))) _Float16 f16x8;
typedef __attribute__((ext_vector_type(4))) _Float16 f16x4;
typedef __attribute__((ext_vector_type(4))) float f32x4;

// log-depth powers: out[s] = E^(s+1)
DEV void powladder_(float E, float* out) {
  float E2 = E * E;
  float E4 = E2 * E2;
  float E8 = E4 * E4;
  float E3 = E2 * E;
  out[0] = E;       out[1] = E2;      out[2] = E3;      out[3] = E4;
  out[4] = E4 * E;  out[5] = E4 * E2; out[6] = E4 * E3; out[7] = E8;
  out[8] = E8 * E;  out[9] = E8 * E2; out[10] = E8 * E3; out[11] = E8 * E4;
  out[12] = E8 * out[4]; out[13] = E8 * out[5]; out[14] = E8 * out[6];
  out[15] = E8 * E8;
}

// 8-deep ladder: out[j] = E^(j+1)
DEV void powladder8_(float E, float* out) {
  float E2 = E * E, E3 = E2 * E, E4 = E2 * E2;
  out[0] = E; out[1] = E2; out[2] = E3; out[3] = E4;
  out[4] = E4 * E; out[5] = E4 * E2; out[6] = E4 * E3; out[7] = E4 * E4;
}

// ---------------- K0: one-shot weight convert + A-table + workspace zero -----
// WH layout (h16): [0,4096) in_W | [4096,7168) xproj_W padded 48 rows |
//                  [7168,9216) out_W | [9216,25600) proj_W
// AVT (f32[1024]) = -exp(A_log).  Zp: SUMYF(2048)+SUMXN(1024) zeroed.
__global__ __launch_bounds__(256) void k0_wcvt(
    const float* __restrict__ in_W, const float* __restrict__ xproj_W,
    const float* __restrict__ out_W, const float* __restrict__ proj_W,
    const float* __restrict__ A_log, h16* __restrict__ WH,
    float* __restrict__ AVT, float* __restrict__ Zp) {
  int tid = blockIdx.x * 256 + threadIdx.x;   // 112*256 = 28672 threads
  if (tid < 3072) Zp[tid] = 0.f;
  if (tid < 1024) AVT[tid] = -__expf(A_log[tid]);
  if (tid < 4096) {
    WH[tid] = (h16)in_W[tid];
  } else if (tid < 7168) {
    int j = tid - 4096;
    int r = j >> 6;
    WH[tid] = (r < 34) ? (h16)xproj_W[r * 64 + (j & 63)] : (h16)0.f;
  } else if (tid < 9216) {
    WH[tid] = (h16)out_W[tid - 7168];
  } else if (tid < 25600) {
    WH[tid] = (h16)proj_W[tid - 9216];
  }
}

// ---------------- K1: LayerNorm1 (B,C,L)->(B,L,C) h16 + token sums -----------
__global__ __launch_bounds__(256) void k1_ln(const float* __restrict__ x,
                                             const float* __restrict__ gn,
                                             const float* __restrict__ bn,
                                             h16* __restrict__ XNH,
                                             float* __restrict__ SUMXN) {
  int bid = blockIdx.x;
  int b = bid >> 6, tile = bid & 63;
  int t0 = tile * 64;
  int tid = threadIdx.x;
  __shared__ float xT[128][65];
  __shared__ float gnS[128], bnS[128];
  __shared__ float red[256];
  if (tid < 128) { gnS[tid] = gn[tid]; bnS[tid] = bn[tid]; }
  for (int k = tid; k < 8192; k += 256) {
    int c = k >> 6, tt = k & 63;
    xT[c][tt] = x[((size_t)(b * C_ + c)) * L_ + t0 + tt];
  }
  __syncthreads();
  {
    int tok = tid >> 2, q = tid & 3;
    float s = 0.f, qq = 0.f;
#pragma unroll
    for (int j = 0; j < 32; ++j) {
      float v = xT[q + 4 * j][tok];
      s += v; qq += v * v;
    }
    s = dpp_add_<0xB1>(s); qq = dpp_add_<0xB1>(qq);
    s = dpp_add_<0x4E>(s); qq = dpp_add_<0x4E>(qq);
    float m = s * (1.f / 128.f);
    float var = qq * (1.f / 128.f) - m * m;
    float rs = rsqrtf(var + 1e-5f);
#pragma unroll
    for (int j = 0; j < 32; ++j) {
      int c = q + 4 * j;
      float v = xT[c][tok];
      xT[c][tok] = (v - m) * rs * gnS[c] + bnS[c];
    }
  }
  __syncthreads();
  float acc = 0.f;
  int cfix = tid & 127;
  for (int k = tid; k < 8192; k += 256) {
    int tt = k >> 7, c = k & 127;
    acc += xT[c][tt];
  }
  // h16 write (coalesced 16B stores)
  for (int k = tid; k < 1024; k += 256) {
    int tt = k >> 4, c8 = (k & 15) * 8;
    f16x8 hv;
#pragma unroll
    for (int j = 0; j < 8; ++j) hv[j] = (_Float16)xT[c8 + j][tt];
    *(f16x8*)&XNH[((size_t)(b * L_ + t0 + tt)) * C_ + c8] = hv;
  }
  red[tid] = acc;
  __syncthreads();
  if (tid < 128) atomicAdd(&SUMXN[b * C_ + cfix], red[tid] + red[tid + 128]);
}

// ---------------- K2: in-proj + conv + silu + x-proj + dt + z + LOCAL SCAN ----
__global__ __launch_bounds__(256) void k2_prep(
    const h16* __restrict__ WH, const float* __restrict__ conv_W,
    const float* __restrict__ conv_b, const float* __restrict__ dt_W,
    const float* __restrict__ dt_b, const float* __restrict__ AVT,
    const h16* __restrict__ XNH, h16* __restrict__ SX2, h16* __restrict__ SDT2,
    h16* __restrict__ SB2, h16* __restrict__ SC2, h16* __restrict__ SZ2,
    float* __restrict__ Pp, float* __restrict__ Qp) {
  int bid = blockIdx.x;
  int i = bid >> 6, tile = bid & 63;
  int b = i >> 2, ch = i & 3;
  int t0 = tile * 64;
  int tid = threadIdx.x;
  int w = __builtin_amdgcn_readfirstlane(tid >> 6);
  int lane = tid & 63;

  __shared__ __attribute__((aligned(16))) union {
    _Float16 uH[80][40];   // rows 0..66 = tokens t0-3..t0+63; 67..79 zero
    float xdS[64][36];     // x-proj output, row=token, col=o (34 used)
    _Float16 zL[64][72];   // silu(z) bounce
  } U;
  __shared__ __attribute__((aligned(16))) _Float16 preH[68][68];  // in-proj out; later dtL
  __shared__ __attribute__((aligned(16))) _Float16 xH[64][72];    // conv+silu out
  __shared__ float convWS[64][4];
  __shared__ float dtWS[64][2];
  __shared__ float dtbS[64], cbS[64];

  convWS[tid >> 2][tid & 3] = conv_W[tid];
  if (tid < 128) dtWS[tid >> 1][tid & 1] = dt_W[tid];
  if (tid < 64) { dtbS[tid] = dt_b[tid]; cbS[tid] = conv_b[tid]; }
  // u from XNH (16B vector loads)
  const h16* xnh = XNH + (size_t)b * L_ * C_ + ch * DM;
  for (int k = tid; k < 320; k += 256) {
    int r = k >> 2, c8 = (k & 3) * 8;
    int tg = t0 - 3 + r;
    f16x8 v = {0, 0, 0, 0, 0, 0, 0, 0};
    if (r < 67 && tg >= 0) v = *(const f16x8*)&xnh[(size_t)tg * C_ + c8];
    *(f16x8*)&U.uH[r][c8] = v;
  }
  __syncthreads();

  int rsel = lane & 15, ksel = (lane >> 4) * 8;
  // in-proj MFMA: wave w owns N-tile nt=w; B-frag direct from WH (L2-hot)
  {
    int nt = w;
    f16x8 bf = *(const f16x8*)&WH[(size_t)(nt * 16 + rsel) * 32 + ksel];
    int row0q = (lane >> 4) << 2;
    int col = nt * 16 + rsel;
#pragma unroll
    for (int mt = 0; mt < 5; ++mt) {
      f16x8 af = *(const f16x8*)&U.uH[mt * 16 + rsel][ksel];
      f32x4 acc = {0.f, 0.f, 0.f, 0.f};
      acc = __builtin_amdgcn_mfma_f32_16x16x32_f16(af, bf, acc, 0, 0, 0);
      int row0 = mt * 16 + row0q;
#pragma unroll
      for (int r = 0; r < 4; ++r) {
        int row = row0 + r;
        if (row < 67) preH[row][col] = (_Float16)acc[r];
      }
    }
  }
  // z-gate MFMA (transposed): D[zd][token]; A-frags direct from WH
  f32x4 zacc[4];
  {
    f16x8 bf = *(const f16x8*)&U.uH[3 + w * 16 + rsel][ksel];
#pragma unroll
    for (int mt = 0; mt < 4; ++mt) {
      f16x8 af = *(const f16x8*)&WH[(size_t)(64 + mt * 16 + rsel) * 32 + ksel];
      f32x4 acc = {0.f, 0.f, 0.f, 0.f};
      zacc[mt] = __builtin_amdgcn_mfma_f32_16x16x32_f16(af, bf, acc, 0, 0, 0);
    }
  }
  __syncthreads();

  // causal depthwise conv + silu; write xH + SX2 inline
  h16* SXp = SX2 + ((size_t)i * L_ + t0) * DI;
  for (int k = tid; k < 4096; k += 256) {
    int r = k >> 6, d = k & 63;
    float v = cbS[d];
#pragma unroll
    for (int j = 0; j < 4; ++j) v = fmaf(convWS[d][j], (float)preH[r + j][d], v);
    v = siluf_(v);
    xH[r][d] = (_Float16)v;
    SXp[(size_t)r * DI + d] = (h16)v;
  }
  __syncthreads();

  // x-proj MFMA: wave w owns M-tile mt=w; B-frags direct from WH
  {
    int mt = w;
    f16x8 a0 = *(const f16x8*)&xH[mt * 16 + rsel][ksel];
    f16x8 a1 = *(const f16x8*)&xH[mt * 16 + rsel][32 + ksel];
    int row0 = mt * 16 + ((lane >> 4) << 2);
#pragma unroll
    for (int nt = 0; nt < 3; ++nt) {
      const h16* wp = WH + 4096 + (size_t)(nt * 16 + rsel) * 64;
      f16x8 b0 = *(const f16x8*)&wp[ksel];
      f16x8 b1 = *(const f16x8*)&wp[32 + ksel];
      f32x4 acc = {0.f, 0.f, 0.f, 0.f};
      acc = __builtin_amdgcn_mfma_f32_16x16x32_f16(a0, b0, acc, 0, 0, 0);
      acc = __builtin_amdgcn_mfma_f32_16x16x32_f16(a1, b1, acc, 0, 0, 0);
      int col = nt * 16 + rsel;
      if (col < 34) {
#pragma unroll
        for (int r = 0; r < 4; ++r) U.xdS[row0 + r][col] = acc[r];
      }
    }
  }
  __syncthreads();

  // dt -> LDS (reuse dead preH, stride 68) + SDT2; B/C writeout
  h16* dtL = (h16*)&preH[0][0];
  h16* SDTp = SDT2 + ((size_t)i * L_ + t0) * DI;
  for (int k = tid; k < 4096; k += 256) {
    int d = k & 63, r = k >> 6;
    float raw = fmaf(U.xdS[r][0], dtWS[d][0], fmaf(U.xdS[r][1], dtWS[d][1], dtbS[d]));
    float dtv = softplusf_(raw);
    dtL[r * 68 + d] = (_Float16)dtv;
    SDTp[(size_t)r * DI + d] = (h16)dtv;
  }
  h16* SBp = SB2 + ((size_t)i * L_ + t0) * DS;
  h16* SCp = SC2 + ((size_t)i * L_ + t0) * DS;
  for (int k = tid; k < 1024; k += 256) {
    int s = k & 15, r = k >> 4;
    SBp[(size_t)r * DS + s] = (h16)U.xdS[r][2 + s];
    SCp[(size_t)r * DS + s] = (h16)U.xdS[r][18 + s];
  }
  __syncthreads();

  // ---- fused local scan: wave w -> seg=w>>1, shalf=w&1, d=lane
  {
    int seg = w >> 1, shalf = w & 1;
    int s0 = shalf * 8;
    float Av[16];
    {
      const float* avp = AVT + lane * 16;
#pragma unroll
      for (int j = 0; j < 4; ++j) *(float4*)&Av[4 * j] = *(const float4*)(avp + 4 * j);
    }
    float A0 = Av[0];
    bool okf = true;
#pragma unroll
    for (int s = 0; s < 16; ++s)
      okf &= fabsf(Av[s] - (float)(s + 1) * A0) <= 1e-4f * fabsf(Av[s]);
    int fastp = __all(okf ? 1 : 0);
    float h[8];
#pragma unroll
    for (int j = 0; j < 8; ++j) h[j] = 0.f;
    float sdt = 0.f;
    int rowbase = seg * SL;
    for (int t = 0; t < SL; ++t) {
      int row = rowbase + t;
      float dt = (float)dtL[row * 68 + lane];
      float xv = (float)xH[row][lane];
      float dtx = dt * xv;
      float dA[8];
      if (fastp) {
        powladder8_(__expf(A0 * dt), dA);
        if (shalf) {
          float E8 = dA[7];
#pragma unroll
          for (int j = 0; j < 8; ++j) dA[j] *= E8;
        }
      } else {
#pragma unroll
        for (int j = 0; j < 8; ++j) dA[j] = __expf(Av[s0 + j] * dt);
      }
      const float* brow = &U.xdS[row][2 + s0];
#pragma unroll
      for (int j = 0; j < 8; ++j) h[j] = fmaf(dA[j], h[j], dtx * brow[j]);
      sdt += dt;
    }
    float P[8];
    if (fastp) {
      powladder8_(__expf(A0 * sdt), P);
      if (shalf) {
        float E8 = P[7];
#pragma unroll
        for (int j = 0; j < 8; ++j) P[j] *= E8;
      }
    } else {
#pragma unroll
      for (int j = 0; j < 8; ++j) P[j] = __expf(Av[s0 + j] * sdt);
    }
    int segg = tile * 2 + seg;
    // seg-major layout: [i][seg][d][s]
    size_t base = (((size_t)i * NSEG + segg) * DI + lane) * DS + s0;
    *(float4*)(Pp + base) = *(float4*)&P[0];
    *(float4*)(Pp + base + 4) = *(float4*)&P[4];
    *(float4*)(Qp + base) = *(float4*)&h[0];
    *(float4*)(Qp + base + 4) = *(float4*)&h[4];
  }
  __syncthreads();   // xdS fully consumed; reuse union as zL

  // z writeout: pack 4 consecutive zd per lane into LDS, then coalesced global
  {
    int tok = w * 16 + rsel;
    int zq = (lane >> 4) << 2;
#pragma unroll
    for (int mt = 0; mt < 4; ++mt) {
      f16x4 pk;
#pragma unroll
      for (int r = 0; r < 4; ++r) pk[r] = (_Float16)siluf_(zacc[mt][r]);
      *(f16x4*)&U.zL[tok][mt * 16 + zq] = pk;
    }
  }
  __syncthreads();
  h16* SZp = SZ2 + ((size_t)i * L_ + t0) * DI;
  for (int k = tid; k < 512; k += 256) {
    int r = k >> 3, dblk = (k & 7) * 8;
    f16x8 v = *(const f16x8*)&U.zL[r][dblk];
    *(f16x8*)&SZp[(size_t)r * DI + dblk] = v;
  }
}

// ---------------- K3b: inter-segment scan (512 blocks x 64 thr: all CUs) ------
__global__ __launch_bounds__(64) void k3b_comb(float* __restrict__ Pp,
                                               const float* __restrict__ Qp) {
  int g = blockIdx.x * 64 + threadIdx.x;  // 32768 = NI*DI*DS
  int ds = g & 1023;       // d*16+s within instance
  int i = g >> 10;
  size_t base = (size_t)i * NSEG * DI * DS + ds;
  constexpr int SST = DI * DS;   // 1024 floats per seg
  float H = 0.f;
  for (int sb = 0; sb < NSEG; sb += 16) {
    float Pv[16], Qv[16];
#pragma unroll
    for (int j = 0; j < 16; ++j) {
      size_t a = base + (size_t)(sb + j) * SST;
      Pv[j] = Pp[a];
      Qv[j] = Qp[a];
    }
#pragma unroll
    for (int j = 0; j < 16; ++j) {
      size_t a = base + (size_t)(sb + j) * SST;
      Pp[a] = H;
      H = fmaf(Pv[j], H, Qv[j]);
    }
  }
}

// ---------------- K3c: final scan, fused with D-term/z-gate-mult/token-sums ----
__global__ __launch_bounds__(256) void k3c_scan(
    const float* __restrict__ AVT, const h16* __restrict__ SDT2,
    const h16* __restrict__ SX2, const h16* __restrict__ SB2,
    const h16* __restrict__ SC2, const h16* __restrict__ SZ2,
    const float* __restrict__ D_p, const float* __restrict__ H0p,
    h16* __restrict__ YS2, float* __restrict__ SUMYF) {
  int bid = blockIdx.x;             // i*32 + sg
  int i = bid >> 5, sg = bid & 31;
  int tid = threadIdx.x;
  int w = tid >> 6, lane = tid & 63;
  int seg = sg * 4 + w;
  int t0 = seg * SL;
  __shared__ float rowS[4][SL][36];   // [w][t][ B16 | C16 ] + pad
  {
    int tk = lane & 31, hf = lane >> 5;
    const h16* p = (hf ? SC2 : SB2) + ((size_t)i * L_ + t0 + tk) * DS;
    float4 r0 = *(const float4*)p;
    float4 r1 = *(const float4*)(p + 8);
    const h16* hp0 = (const h16*)&r0;
    const h16* hp1 = (const h16*)&r1;
#pragma unroll
    for (int s = 0; s < 8; ++s) {
      rowS[w][tk][hf * 16 + s] = (float)hp0[s];
      rowS[w][tk][hf * 16 + 8 + s] = (float)hp1[s];
    }
  }
  __syncthreads();
  float Av[16];
  {
    const float* avp = AVT + lane * 16;
#pragma unroll
    for (int j = 0; j < 4; ++j) *(float4*)&Av[4 * j] = *(const float4*)(avp + 4 * j);
  }
  float A0 = Av[0];
  bool okf = true;
#pragma unroll
  for (int s = 0; s < 16; ++s) okf &= fabsf(Av[s] - (float)(s + 1) * A0) <= 1e-4f * fabsf(Av[s]);
  int fastp = __all(okf ? 1 : 0);
  float Dp = D_p[lane];
  float h[16];
  {
    size_t base = (((size_t)i * NSEG + seg) * DI + lane) * DS;
#pragma unroll
    for (int j = 0; j < 4; ++j) *(float4*)&h[4 * j] = *(const float4*)(H0p + base + 4 * j);
  }
  const h16* pdt = SDT2 + ((size_t)i * L_ + t0) * DI + lane;
  const h16* pxx = SX2 + ((size_t)i * L_ + t0) * DI + lane;
  const h16* pzz = SZ2 + ((size_t)i * L_ + t0) * DI + lane;
  h16* pys = YS2 + ((size_t)i * L_ + t0) * DI + lane;
  float dtc = (float)pdt[0], xvc = (float)pxx[0], zvc = (float)pzz[0];
  float sum = 0.f;
  for (int t = 0; t < SL; ++t) {
    float dt = dtc, xv = xvc, zv = zvc;
    if (t < SL - 1) {
      dtc = (float)pdt[(t + 1) * DI];
      xvc = (float)pxx[(t + 1) * DI];
      zvc = (float)pzz[(t + 1) * DI];
    }
    const float* row = &rowS[w][t][0];
    float Bv[16], Cv[16];
#pragma unroll
    for (int j = 0; j < 4; ++j) {
      *(float4*)&Bv[4 * j] = *(const float4*)(row + 4 * j);
      *(float4*)&Cv[4 * j] = *(const float4*)(row + 16 + 4 * j);
    }
    float dtx = dt * xv;
    float dA[16];
    if (fastp) {
      powladder_(__expf(A0 * dt), dA);
    } else {
#pragma unroll
      for (int s = 0; s < 16; ++s) dA[s] = __expf(Av[s] * dt);
    }
    float y0 = 0.f, y1 = 0.f, y2 = 0.f, y3 = 0.f;
#pragma unroll
    for (int s = 0; s < 16; s += 4) {
      h[s] = fmaf(dA[s], h[s], dtx * Bv[s]);       y0 = fmaf(h[s], Cv[s], y0);
      h[s + 1] = fmaf(dA[s + 1], h[s + 1], dtx * Bv[s + 1]); y1 = fmaf(h[s + 1], Cv[s + 1], y1);
      h[s + 2] = fmaf(dA[s + 2], h[s + 2], dtx * Bv[s + 2]); y2 = fmaf(h[s + 2], Cv[s + 2], y2);
      h[s + 3] = fmaf(dA[s + 3], h[s + 3], dtx * Bv[s + 3]); y3 = fmaf(h[s + 3], Cv[s + 3], y3);
    }
    float y = (y0 + y1) + (y2 + y3);
    float yf = fmaf(xv, Dp, y) * zv;
    pys[(size_t)t * DI] = (h16)yf;
    sum += yf;
  }
  atomicAdd(&SUMYF[i * DI + lane], sum);
}

// ---------------- K56: SE gates + gated combine (MFMA) + LN2 + proj (MFMA) ----
// Weights pre-h16 in WH: owH/projH are pure vector copies (no per-block cvt).
__global__ __launch_bounds__(256) void k56_comb_proj(
    const float* __restrict__ out_W, const float* __restrict__ skip_p,
    const float* __restrict__ se_W1, const float* __restrict__ se_W2,
    const float* __restrict__ SUMYF, const float* __restrict__ SUMXN,
    const h16* __restrict__ YS2, const float* __restrict__ gn,
    const float* __restrict__ bn, const h16* __restrict__ WH,
    const float* __restrict__ proj_b, const h16* __restrict__ XNH,
    float* __restrict__ out) {
  int bid = blockIdx.x;
  int b = bid >> 6, tile = bid & 63;
  int t0 = tile * 64;
  int tid = threadIdx.x;
  int w = __builtin_amdgcn_readfirstlane(tid >> 6);
  int lane = tid & 63;
  __shared__ __attribute__((aligned(16))) union {
    float xmS[64][132];
    _Float16 projH[64][136];   // one 64-row half of proj_W per pass
  } U;
  __shared__ __attribute__((aligned(16))) union {
    struct {
      _Float16 yH[64][72];
      _Float16 owH[32][72];
    } pre;
    _Float16 xmH[64][136];
  } V;
  __shared__ float gAll[4][64];
  __shared__ float gnS[128], bnS[128];
  float* catS = (float*)&V.pre.yH[0][0];   // 4*64 floats
  float* seL = catS + 256;                 // 8 floats

  if (tid < 128) { gnS[tid] = gn[tid]; bnS[tid] = bn[tid]; }
  // owH: h16 vector copy from WH[7168..9216)
  for (int k = tid; k < 256; k += 256) {
    int r = k >> 3, c8 = (k & 7) * 8;
    *(f16x8*)&V.pre.owH[r][c8] = *(const f16x8*)&WH[7168 + r * 64 + c8];
  }
  // stage xm from XNH (h16 -> f32)
  const h16* xmh = XNH + (size_t)b * L_ * C_;
  for (int k = tid; k < 1024; k += 256) {
    int tt = k >> 4, c8 = (k & 15) * 8;
    f16x8 hv = *(const f16x8*)&xmh[(size_t)(t0 + tt) * C_ + c8];
#pragma unroll
    for (int j = 0; j < 8; ++j) U.xmS[tt][c8 + j] = (float)hv[j];
  }
  // ---- gates (folded k4): phase A -> catS
  {
    int ch = tid >> 6, j = tid & 63;
    float invL = 1.f / (float)L_;
    if (j < 32) {
      const float* sy = SUMYF + (b * 4 + ch) * DI;
      const float* ow = out_W + j * 64;
      float acc = 0.f;
#pragma unroll
      for (int dd = 0; dd < 64; ++dd) acc = fmaf(sy[dd], ow[dd], acc);
      catS[ch * 64 + j] = acc * invL;
    } else {
      catS[ch * 64 + j] = skip_p[0] * SUMXN[b * C_ + ch * DM + (j - 32)] * invL;
    }
  }
  __syncthreads();
  if (tid < 8) {
    int ch = tid >> 1, r = tid & 1;
    float acc = 0.f;
#pragma unroll
    for (int k = 0; k < 64; ++k) acc = fmaf(catS[ch * 64 + k], se_W1[r * 64 + k], acc);
    seL[tid] = fmaxf(acc, 0.f);
  }
  __syncthreads();
  {
    int ch = tid >> 6, j = tid & 63;
    gAll[ch][j] = sigmoidf_(fmaf(seL[ch * 2], se_W2[j * 2], seL[ch * 2 + 1] * se_W2[j * 2 + 1]));
  }
  __syncthreads();   // gates done; yH region reusable (owH must be re-kept)
  // owH was overlaid by catS/seL (first 264 floats = rows 0..7 of yH); owH is
  // at yH[64..] region -> untouched. catS used yH rows only. Safe.

  int rsel = lane & 15, ksel = (lane >> 4) * 8;
  float skip = skip_p[0];
  // per-channel gated combine: xm[tok][ch*32+o] = g1*M1 + g2*skip*xn
  for (int ch = 0; ch < 4; ++ch) {
    const h16* py = YS2 + ((size_t)(b * 4 + ch) * L_ + t0) * DI;
    for (int k = tid; k < 512; k += 256) {
      int tt = k >> 3, dblk = (k & 7) * 8;
      *(f16x8*)&V.pre.yH[tt][dblk] = *(const f16x8*)&py[(size_t)tt * DI + dblk];
    }
    __syncthreads();
    f16x8 a0 = *(const f16x8*)&V.pre.yH[w * 16 + rsel][ksel];
    f16x8 a1 = *(const f16x8*)&V.pre.yH[w * 16 + rsel][32 + ksel];
    int row0 = w * 16 + ((lane >> 4) << 2);
#pragma unroll
    for (int nt = 0; nt < 2; ++nt) {
      f16x8 b0 = *(const f16x8*)&V.pre.owH[nt * 16 + rsel][ksel];
      f16x8 b1 = *(const f16x8*)&V.pre.owH[nt * 16 + rsel][32 + ksel];
      f32x4 acc = {0.f, 0.f, 0.f, 0.f};
      acc = __builtin_amdgcn_mfma_f32_16x16x32_f16(a0, b0, acc, 0, 0, 0);
      acc = __builtin_amdgcn_mfma_f32_16x16x32_f16(a1, b1, acc, 0, 0, 0);
      int o = nt * 16 + rsel;
      float g1 = gAll[ch][o], g2s = gAll[ch][32 + o] * skip;
      int cc = ch * 32 + o;
#pragma unroll
      for (int r = 0; r < 4; ++r) {
        int tok = row0 + r;
        U.xmS[tok][cc] = g1 * acc[r] + g2s * U.xmS[tok][cc];
      }
    }
    __syncthreads();
  }

  // LN2 over xm rows
  {
    int tok = tid >> 2, q = tid & 3;
    float s = 0.f, qq = 0.f;
#pragma unroll
    for (int j = 0; j < 32; ++j) {
      float v = U.xmS[tok][4 * j + q];
      s += v; qq += v * v;
    }
    s = dpp_add_<0xB1>(s); qq = dpp_add_<0xB1>(qq);
    s = dpp_add_<0x4E>(s); qq = dpp_add_<0x4E>(qq);
    float m = s * (1.f / 128.f);
    float var = qq * (1.f / 128.f) - m * m;
    float rs = rsqrtf(var + 1e-5f);
#pragma unroll
    for (int j = 0; j < 32; ++j) {
      int c = 4 * j + q;
      float v = U.xmS[tok][c];
      U.xmS[tok][c] = (v - m) * rs * gnS[c] + bnS[c];
    }
  }
  __syncthreads();
  // convert LN output to h16 (xmH overlays dead yH/owH)
  for (int k = tid; k < 1024; k += 256) {
    int tt = k >> 4, cblk = (k & 15) * 8;
    float4 v0 = *(const float4*)&U.xmS[tt][cblk];
    float4 v1 = *(const float4*)&U.xmS[tt][cblk + 4];
    f16x8 hv;
    hv[0] = (_Float16)v0.x; hv[1] = (_Float16)v0.y;
    hv[2] = (_Float16)v0.z; hv[3] = (_Float16)v0.w;
    hv[4] = (_Float16)v1.x; hv[5] = (_Float16)v1.y;
    hv[6] = (_Float16)v1.z; hv[7] = (_Float16)v1.w;
    *(f16x8*)&V.xmH[tt][cblk] = hv;
  }
  __syncthreads();
  // proj MFMA in two 64-output-row passes (projH = h16 copy from WH)
  f16x8 af[4];
#pragma unroll
  for (int kc = 0; kc < 4; ++kc)
    af[kc] = *(const f16x8*)&V.xmH[w * 16 + rsel][kc * 32 + ksel];
  int row0 = w * 16 + ((lane >> 4) << 2);
#pragma unroll
  for (int half = 0; half < 2; ++half) {
    for (int k = tid; k < 1024; k += 256) {
      int o = k >> 4, cblk = (k & 15) * 8;
      *(f16x8*)&U.projH[o][cblk] =
          *(const f16x8*)&WH[9216 + (half * 64 + o) * 128 + cblk];
    }
    __syncthreads();
#pragma unroll
    for (int nt = 0; nt < 4; ++nt) {
      int ol = nt * 16 + rsel;
      int o = half * 64 + ol;
      float pb = proj_b[o];
      f32x4 acc = {pb, pb, pb, pb};
#pragma unroll
      for (int kc = 0; kc < 4; ++kc) {
        f16x8 bf = *(const f16x8*)&U.projH[ol][kc * 32 + ksel];
        acc = __builtin_amdgcn_mfma_f32_16x16x32_f16(af[kc], bf, acc, 0, 0, 0);
      }
      *(float4*)&out[((size_t)(b * OUT_ + o)) * L_ + t0 + row0] =
          make_float4(acc[0], acc[1], acc[2], acc[3]);
    }
    __syncthreads();
  }
}

extern "C" void kernel_launch(void* const* d_in, const int* in_sizes, int n_in,
                              void* d_out, int out_size, void* d_ws, size_t ws_size,
                              hipStream_t stream) {
  const float* x = (const float*)d_in[0];
  const float* norm_g = (const float*)d_in[1];
  const float* norm_b = (const float*)d_in[2];
  const float* proj_W = (const float*)d_in[3];
  const float* proj_b = (const float*)d_in[4];
  const float* skip = (const float*)d_in[5];
  const float* se_W1 = (const float*)d_in[6];
  const float* se_W2 = (const float*)d_in[7];
  const float* in_W = (const float*)d_in[8];
  const float* conv_W = (const float*)d_in[9];
  const float* conv_b = (const float*)d_in[10];
  const float* xproj_W = (const float*)d_in[11];
  const float* dt_W = (const float*)d_in[12];
  const float* dt_b = (const float*)d_in[13];
  const float* A_log = (const float*)d_in[14];
  const float* D_p = (const float*)d_in[15];
  const float* out_W = (const float*)d_in[16];
  float* out = (float*)d_out;

  // workspace (~120 MiB)
  float* SUMYF = (float*)d_ws;                      // NI*DI
  float* SUMXN = SUMYF + NI * DI;                   // B*C
  float* Pp = SUMXN + B_ * C_;                      // NI*NSEG*DI*DS f32 (seg-major)
  float* Qp = Pp + (size_t)NI * DI * NSEG * DS;
  h16* YS2 = (h16*)(Qp + (size_t)NI * DI * NSEG * DS);  // NI*L*DI h16
  h16* SX2 = YS2 + (size_t)NI * L_ * DI;
  h16* SDT2 = SX2 + (size_t)NI * L_ * DI;
  h16* SB2 = SDT2 + (size_t)NI * L_ * DI;           // NI*L*DS h16
  h16* SC2 = SB2 + (size_t)NI * L_ * DS;
  h16* SZ2 = SC2 + (size_t)NI * L_ * DS;            // NI*L*DI h16 (silu(z))
  h16* XNH = SZ2 + (size_t)NI * L_ * DI;            // B*L*C h16
  h16* WH = XNH + (size_t)B_ * L_ * C_;             // 25600 h16 (all weights)
  float* AVT = (float*)(WH + 25600);                // 1024 f32 = -exp(A_log)

  k0_wcvt<<<112, 256, 0, stream>>>(in_W, xproj_W, out_W, proj_W, A_log, WH, AVT,
                                   SUMYF);
  k1_ln<<<B_ * 64, 256, 0, stream>>>(x, norm_g, norm_b, XNH, SUMXN);
  k2_prep<<<NI * 64, 256, 0, stream>>>(WH, conv_W, conv_b, dt_W, dt_b, AVT,
                                       XNH, SX2, SDT2, SB2, SC2, SZ2, Pp, Qp);
  k3b_comb<<<512, 64, 0, stream>>>(Pp, Qp);
  k3c_scan<<<NI * 32, 256, 0, stream>>>(AVT, SDT2, SX2, SB2, SC2, SZ2, D_p,
                                        Pp, YS2, SUMYF);
  k56_comb_proj<<<B_ * 64, 256, 0, stream>>>(out_W, skip, se_W1, se_W2, SUMYF,
                                             SUMXN, YS2, norm_g, norm_b, WH,
                                             proj_b, XNH, out);
}

// Round 11
// 204.820 us; speedup vs baseline: 1.0474x; 1.0265x over previous
//
#include <hip/hip_runtime.h>
#include <math.h>

typedef _Float16 h16;

#define DEV static __device__ __forceinline__

constexpr int B_ = 8, C_ = 128, L_ = 4096, OUT_ = 128;
constexpr int NCH = 4, DM = 32, DS = 16, DI = 64;
constexpr int NI = 32;            // B_*NCH instances
constexpr int NSEG = 128;         // scan segments
constexpr int SL = L_ / NSEG;     // 32 steps per segment

DEV float sigmoidf_(float x) { return 1.f / (1.f + __expf(-x)); }
DEV float siluf_(float x) { return x * sigmoidf_(x); }
DEV float softplusf_(float x) { return (x > 20.f) ? x : __logf(1.f + __expf(x)); }

template <int CTRL>
DEV float dpp_add_(float x) {
  int v = __builtin_amdgcn_update_dpp(0, __float_as_int(x), CTRL, 0xf, 0xf, false);
  return x + __int_as_float(v);
}

typedef __attribute__((ext_vector_type(8))) _Float16 f16x8;
typedef __attribute__((ext_vector_type(4))) _Float16 f16x4;
typedef __attribute__((ext_vector_type(4))) float f32x4;

// log-depth powers: out[s] = E^(s+1)
DEV void powladder_(float E, float* out) {
  float E2 = E * E;
  float E4 = E2 * E2;
  float E8 = E4 * E4;
  float E3 = E2 * E;
  out[0] = E;       out[1] = E2;      out[2] = E3;      out[3] = E4;
  out[4] = E4 * E;  out[5] = E4 * E2; out[6] = E4 * E3; out[7] = E8;
  out[8] = E8 * E;  out[9] = E8 * E2; out[10] = E8 * E3; out[11] = E8 * E4;
  out[12] = E8 * out[4]; out[13] = E8 * out[5]; out[14] = E8 * out[6];
  out[15] = E8 * E8;
}

// 8-deep ladder: out[j] = E^(j+1)
DEV void powladder8_(float E, float* out) {
  float E2 = E * E, E3 = E2 * E, E4 = E2 * E2;
  out[0] = E; out[1] = E2; out[2] = E3; out[3] = E4;
  out[4] = E4 * E; out[5] = E4 * E2; out[6] = E4 * E3; out[7] = E4 * E4;
}

// ---------------- K1: LayerNorm1 + merged weight-convert tail blocks ---------
// Blocks [0, 512): LN tile work. Blocks [512, 616): convert weights -> WH/AVT.
// WH layout (h16): [0,4096) in_W | [4096,7168) xproj_W padded 48 rows |
//                  [7168,9216) out_W | [9216,25600) proj_W
__global__ __launch_bounds__(256) void k1_ln(
    const float* __restrict__ x, const float* __restrict__ gn,
    const float* __restrict__ bn, const float* __restrict__ in_W,
    const float* __restrict__ xproj_W, const float* __restrict__ out_W,
    const float* __restrict__ proj_W, const float* __restrict__ A_log,
    h16* __restrict__ WH, float* __restrict__ AVT, h16* __restrict__ XNH,
    float* __restrict__ SUMXN) {
  int bid = blockIdx.x;
  int tid = threadIdx.x;
  if (bid >= B_ * 64) {
    int g = (bid - B_ * 64) * 256 + tid;
    if (g < 1024) AVT[g] = -__expf(A_log[g]);
    if (g < 4096) {
      WH[g] = (h16)in_W[g];
    } else if (g < 7168) {
      int j = g - 4096;
      int r = j >> 6;
      WH[g] = (r < 34) ? (h16)xproj_W[r * 64 + (j & 63)] : (h16)0.f;
    } else if (g < 9216) {
      WH[g] = (h16)out_W[g - 7168];
    } else if (g < 25600) {
      WH[g] = (h16)proj_W[g - 9216];
    }
    return;
  }
  int b = bid >> 6, tile = bid & 63;
  int t0 = tile * 64;
  __shared__ float xT[128][65];
  __shared__ float gnS[128], bnS[128];
  __shared__ float red[256];
  if (tid < 128) { gnS[tid] = gn[tid]; bnS[tid] = bn[tid]; }
  for (int k = tid; k < 8192; k += 256) {
    int c = k >> 6, tt = k & 63;
    xT[c][tt] = x[((size_t)(b * C_ + c)) * L_ + t0 + tt];
  }
  __syncthreads();
  {
    int tok = tid >> 2, q = tid & 3;
    float s = 0.f, qq = 0.f;
#pragma unroll
    for (int j = 0; j < 32; ++j) {
      float v = xT[q + 4 * j][tok];
      s += v; qq += v * v;
    }
    s = dpp_add_<0xB1>(s); qq = dpp_add_<0xB1>(qq);
    s = dpp_add_<0x4E>(s); qq = dpp_add_<0x4E>(qq);
    float m = s * (1.f / 128.f);
    float var = qq * (1.f / 128.f) - m * m;
    float rs = rsqrtf(var + 1e-5f);
#pragma unroll
    for (int j = 0; j < 32; ++j) {
      int c = q + 4 * j;
      float v = xT[c][tok];
      xT[c][tok] = (v - m) * rs * gnS[c] + bnS[c];
    }
  }
  __syncthreads();
  float acc = 0.f;
  int cfix = tid & 127;
  for (int k = tid; k < 8192; k += 256) {
    int tt = k >> 7, c = k & 127;
    acc += xT[c][tt];
  }
  // h16 write (coalesced 16B stores)
  for (int k = tid; k < 1024; k += 256) {
    int tt = k >> 4, c8 = (k & 15) * 8;
    f16x8 hv;
#pragma unroll
    for (int j = 0; j < 8; ++j) hv[j] = (_Float16)xT[c8 + j][tt];
    *(f16x8*)&XNH[((size_t)(b * L_ + t0 + tt)) * C_ + c8] = hv;
  }
  red[tid] = acc;
  __syncthreads();
  if (tid < 128) atomicAdd(&SUMXN[b * C_ + cfix], red[tid] + red[tid + 128]);
}

// ---------------- K2: in-proj + conv + silu + x-proj + dt + z + LOCAL SCAN ----
// P/Q carries stored h16 (halves carry traffic).
__global__ __launch_bounds__(256) void k2_prep(
    const h16* __restrict__ WH, const float* __restrict__ conv_W,
    const float* __restrict__ conv_b, const float* __restrict__ dt_W,
    const float* __restrict__ dt_b, const float* __restrict__ AVT,
    const h16* __restrict__ XNH, h16* __restrict__ SX2, h16* __restrict__ SDT2,
    h16* __restrict__ SB2, h16* __restrict__ SC2, h16* __restrict__ SZ2,
    h16* __restrict__ Pp, h16* __restrict__ Qp) {
  int bid = blockIdx.x;
  int i = bid >> 6, tile = bid & 63;
  int b = i >> 2, ch = i & 3;
  int t0 = tile * 64;
  int tid = threadIdx.x;
  int w = __builtin_amdgcn_readfirstlane(tid >> 6);
  int lane = tid & 63;

  __shared__ __attribute__((aligned(16))) union {
    _Float16 uH[80][40];   // rows 0..66 = tokens t0-3..t0+63; 67..79 zero
    float xdS[64][36];     // x-proj output, row=token, col=o (34 used)
    _Float16 zL[64][72];   // silu(z) bounce
  } U;
  __shared__ __attribute__((aligned(16))) _Float16 preH[68][68];  // in-proj out; later dtL
  __shared__ __attribute__((aligned(16))) _Float16 xH[64][72];    // conv+silu out
  __shared__ float convWS[64][4];
  __shared__ float dtWS[64][2];
  __shared__ float dtbS[64], cbS[64];

  convWS[tid >> 2][tid & 3] = conv_W[tid];
  if (tid < 128) dtWS[tid >> 1][tid & 1] = dt_W[tid];
  if (tid < 64) { dtbS[tid] = dt_b[tid]; cbS[tid] = conv_b[tid]; }
  // u from XNH (16B vector loads)
  const h16* xnh = XNH + (size_t)b * L_ * C_ + ch * DM;
  for (int k = tid; k < 320; k += 256) {
    int r = k >> 2, c8 = (k & 3) * 8;
    int tg = t0 - 3 + r;
    f16x8 v = {0, 0, 0, 0, 0, 0, 0, 0};
    if (r < 67 && tg >= 0) v = *(const f16x8*)&xnh[(size_t)tg * C_ + c8];
    *(f16x8*)&U.uH[r][c8] = v;
  }
  __syncthreads();

  int rsel = lane & 15, ksel = (lane >> 4) * 8;
  // in-proj MFMA: wave w owns N-tile nt=w; B-frag direct from WH (L2-hot)
  {
    int nt = w;
    f16x8 bf = *(const f16x8*)&WH[(size_t)(nt * 16 + rsel) * 32 + ksel];
    int row0q = (lane >> 4) << 2;
    int col = nt * 16 + rsel;
#pragma unroll
    for (int mt = 0; mt < 5; ++mt) {
      f16x8 af = *(const f16x8*)&U.uH[mt * 16 + rsel][ksel];
      f32x4 acc = {0.f, 0.f, 0.f, 0.f};
      acc = __builtin_amdgcn_mfma_f32_16x16x32_f16(af, bf, acc, 0, 0, 0);
      int row0 = mt * 16 + row0q;
#pragma unroll
      for (int r = 0; r < 4; ++r) {
        int row = row0 + r;
        if (row < 67) preH[row][col] = (_Float16)acc[r];
      }
    }
  }
  // z-gate MFMA (transposed): D[zd][token]; A-frags direct from WH
  f32x4 zacc[4];
  {
    f16x8 bf = *(const f16x8*)&U.uH[3 + w * 16 + rsel][ksel];
#pragma unroll
    for (int mt = 0; mt < 4; ++mt) {
      f16x8 af = *(const f16x8*)&WH[(size_t)(64 + mt * 16 + rsel) * 32 + ksel];
      f32x4 acc = {0.f, 0.f, 0.f, 0.f};
      zacc[mt] = __builtin_amdgcn_mfma_f32_16x16x32_f16(af, bf, acc, 0, 0, 0);
    }
  }
  __syncthreads();

  // causal depthwise conv + silu; write xH + SX2 inline
  h16* SXp = SX2 + ((size_t)i * L_ + t0) * DI;
  for (int k = tid; k < 4096; k += 256) {
    int r = k >> 6, d = k & 63;
    float v = cbS[d];
#pragma unroll
    for (int j = 0; j < 4; ++j) v = fmaf(convWS[d][j], (float)preH[r + j][d], v);
    v = siluf_(v);
    xH[r][d] = (_Float16)v;
    SXp[(size_t)r * DI + d] = (h16)v;
  }
  __syncthreads();

  // x-proj MFMA: wave w owns M-tile mt=w; B-frags direct from WH
  {
    int mt = w;
    f16x8 a0 = *(const f16x8*)&xH[mt * 16 + rsel][ksel];
    f16x8 a1 = *(const f16x8*)&xH[mt * 16 + rsel][32 + ksel];
    int row0 = mt * 16 + ((lane >> 4) << 2);
#pragma unroll
    for (int nt = 0; nt < 3; ++nt) {
      const h16* wp = WH + 4096 + (size_t)(nt * 16 + rsel) * 64;
      f16x8 b0 = *(const f16x8*)&wp[ksel];
      f16x8 b1 = *(const f16x8*)&wp[32 + ksel];
      f32x4 acc = {0.f, 0.f, 0.f, 0.f};
      acc = __builtin_amdgcn_mfma_f32_16x16x32_f16(a0, b0, acc, 0, 0, 0);
      acc = __builtin_amdgcn_mfma_f32_16x16x32_f16(a1, b1, acc, 0, 0, 0);
      int col = nt * 16 + rsel;
      if (col < 34) {
#pragma unroll
        for (int r = 0; r < 4; ++r) U.xdS[row0 + r][col] = acc[r];
      }
    }
  }
  __syncthreads();

  // dt -> LDS (reuse dead preH, stride 68) + SDT2; B/C writeout
  h16* dtL = (h16*)&preH[0][0];
  h16* SDTp = SDT2 + ((size_t)i * L_ + t0) * DI;
  for (int k = tid; k < 4096; k += 256) {
    int d = k & 63, r = k >> 6;
    float raw = fmaf(U.xdS[r][0], dtWS[d][0], fmaf(U.xdS[r][1], dtWS[d][1], dtbS[d]));
    float dtv = softplusf_(raw);
    dtL[r * 68 + d] = (_Float16)dtv;
    SDTp[(size_t)r * DI + d] = (h16)dtv;
  }
  h16* SBp = SB2 + ((size_t)i * L_ + t0) * DS;
  h16* SCp = SC2 + ((size_t)i * L_ + t0) * DS;
  for (int k = tid; k < 1024; k += 256) {
    int s = k & 15, r = k >> 4;
    SBp[(size_t)r * DS + s] = (h16)U.xdS[r][2 + s];
    SCp[(size_t)r * DS + s] = (h16)U.xdS[r][18 + s];
  }
  __syncthreads();

  // ---- fused local scan: wave w -> seg=w>>1, shalf=w&1, d=lane
  {
    int seg = w >> 1, shalf = w & 1;
    int s0 = shalf * 8;
    float Av[16];
    {
      const float* avp = AVT + lane * 16;
#pragma unroll
      for (int j = 0; j < 4; ++j) *(float4*)&Av[4 * j] = *(const float4*)(avp + 4 * j);
    }
    float A0 = Av[0];
    bool okf = true;
#pragma unroll
    for (int s = 0; s < 16; ++s)
      okf &= fabsf(Av[s] - (float)(s + 1) * A0) <= 1e-4f * fabsf(Av[s]);
    int fastp = __all(okf ? 1 : 0);
    float h[8];
#pragma unroll
    for (int j = 0; j < 8; ++j) h[j] = 0.f;
    float sdt = 0.f;
    int rowbase = seg * SL;
    for (int t = 0; t < SL; ++t) {
      int row = rowbase + t;
      float dt = (float)dtL[row * 68 + lane];
      float xv = (float)xH[row][lane];
      float dtx = dt * xv;
      float dA[8];
      if (fastp) {
        powladder8_(__expf(A0 * dt), dA);
        if (shalf) {
          float E8 = dA[7];
#pragma unroll
          for (int j = 0; j < 8; ++j) dA[j] *= E8;
        }
      } else {
#pragma unroll
        for (int j = 0; j < 8; ++j) dA[j] = __expf(Av[s0 + j] * dt);
      }
      const float* brow = &U.xdS[row][2 + s0];
#pragma unroll
      for (int j = 0; j < 8; ++j) h[j] = fmaf(dA[j], h[j], dtx * brow[j]);
      sdt += dt;
    }
    float P[8];
    if (fastp) {
      powladder8_(__expf(A0 * sdt), P);
      if (shalf) {
        float E8 = P[7];
#pragma unroll
        for (int j = 0; j < 8; ++j) P[j] *= E8;
      }
    } else {
#pragma unroll
      for (int j = 0; j < 8; ++j) P[j] = __expf(Av[s0 + j] * sdt);
    }
    int segg = tile * 2 + seg;
    // seg-major h16 layout: [i][seg][d][s]
    size_t base = (((size_t)i * NSEG + segg) * DI + lane) * DS + s0;
    f16x8 ph, qh;
#pragma unroll
    for (int j = 0; j < 8; ++j) { ph[j] = (_Float16)P[j]; qh[j] = (_Float16)h[j]; }
    *(f16x8*)(Pp + base) = ph;
    *(f16x8*)(Qp + base) = qh;
  }
  __syncthreads();   // xdS fully consumed; reuse union as zL

  // z writeout: pack 4 consecutive zd per lane into LDS, then coalesced global
  {
    int tok = w * 16 + rsel;
    int zq = (lane >> 4) << 2;
#pragma unroll
    for (int mt = 0; mt < 4; ++mt) {
      f16x4 pk;
#pragma unroll
      for (int r = 0; r < 4; ++r) pk[r] = (_Float16)siluf_(zacc[mt][r]);
      *(f16x4*)&U.zL[tok][mt * 16 + zq] = pk;
    }
  }
  __syncthreads();
  h16* SZp = SZ2 + ((size_t)i * L_ + t0) * DI;
  for (int k = tid; k < 512; k += 256) {
    int r = k >> 3, dblk = (k & 7) * 8;
    f16x8 v = *(const f16x8*)&U.zL[r][dblk];
    *(f16x8*)&SZp[(size_t)r * DI + dblk] = v;
  }
}

// ---------------- K3b: inter-segment scan (h16 P/Q, f32 accumulate) -----------
__global__ __launch_bounds__(64) void k3b_comb(h16* __restrict__ Pp,
                                               const h16* __restrict__ Qp) {
  int g = blockIdx.x * 64 + threadIdx.x;  // 32768 = NI*DI*DS
  int ds = g & 1023;       // d*16+s within instance
  int i = g >> 10;
  size_t base = (size_t)i * NSEG * DI * DS + ds;
  constexpr int SST = DI * DS;   // 1024 elems per seg
  float H = 0.f;
  for (int sb = 0; sb < NSEG; sb += 16) {
    float Pv[16], Qv[16];
#pragma unroll
    for (int j = 0; j < 16; ++j) {
      size_t a = base + (size_t)(sb + j) * SST;
      Pv[j] = (float)Pp[a];
      Qv[j] = (float)Qp[a];
    }
#pragma unroll
    for (int j = 0; j < 16; ++j) {
      size_t a = base + (size_t)(sb + j) * SST;
      Pp[a] = (h16)H;
      H = fmaf(Pv[j], H, Qv[j]);
    }
  }
}

// ---------------- K3c: final scan, fused with D-term/z-gate-mult/token-sums ----
__global__ __launch_bounds__(256) void k3c_scan(
    const float* __restrict__ AVT, const h16* __restrict__ SDT2,
    const h16* __restrict__ SX2, const h16* __restrict__ SB2,
    const h16* __restrict__ SC2, const h16* __restrict__ SZ2,
    const float* __restrict__ D_p, const h16* __restrict__ H0p,
    h16* __restrict__ YS2, float* __restrict__ SUMYF) {
  int bid = blockIdx.x;             // i*32 + sg
  int i = bid >> 5, sg = bid & 31;
  int tid = threadIdx.x;
  int w = tid >> 6, lane = tid & 63;
  int seg = sg * 4 + w;
  int t0 = seg * SL;
  __shared__ float rowS[4][SL][36];   // [w][t][ B16 | C16 ] + pad
  {
    int tk = lane & 31, hf = lane >> 5;
    const h16* p = (hf ? SC2 : SB2) + ((size_t)i * L_ + t0 + tk) * DS;
    float4 r0 = *(const float4*)p;
    float4 r1 = *(const float4*)(p + 8);
    const h16* hp0 = (const h16*)&r0;
    const h16* hp1 = (const h16*)&r1;
#pragma unroll
    for (int s = 0; s < 8; ++s) {
      rowS[w][tk][hf * 16 + s] = (float)hp0[s];
      rowS[w][tk][hf * 16 + 8 + s] = (float)hp1[s];
    }
  }
  __syncthreads();
  float Av[16];
  {
    const float* avp = AVT + lane * 16;
#pragma unroll
    for (int j = 0; j < 4; ++j) *(float4*)&Av[4 * j] = *(const float4*)(avp + 4 * j);
  }
  float A0 = Av[0];
  bool okf = true;
#pragma unroll
  for (int s = 0; s < 16; ++s) okf &= fabsf(Av[s] - (float)(s + 1) * A0) <= 1e-4f * fabsf(Av[s]);
  int fastp = __all(okf ? 1 : 0);
  float Dp = D_p[lane];
  float h[16];
  {
    const h16* hp = H0p + (((size_t)i * NSEG + seg) * DI + lane) * DS;
    f16x8 h0a = *(const f16x8*)hp;
    f16x8 h0b = *(const f16x8*)(hp + 8);
#pragma unroll
    for (int j = 0; j < 8; ++j) { h[j] = (float)h0a[j]; h[8 + j] = (float)h0b[j]; }
  }
  const h16* pdt = SDT2 + ((size_t)i * L_ + t0) * DI + lane;
  const h16* pxx = SX2 + ((size_t)i * L_ + t0) * DI + lane;
  const h16* pzz = SZ2 + ((size_t)i * L_ + t0) * DI + lane;
  h16* pys = YS2 + ((size_t)i * L_ + t0) * DI + lane;
  float dtc = (float)pdt[0], xvc = (float)pxx[0], zvc = (float)pzz[0];
  float sum = 0.f;
  for (int t = 0; t < SL; ++t) {
    float dt = dtc, xv = xvc, zv = zvc;
    if (t < SL - 1) {
      dtc = (float)pdt[(t + 1) * DI];
      xvc = (float)pxx[(t + 1) * DI];
      zvc = (float)pzz[(t + 1) * DI];
    }
    const float* row = &rowS[w][t][0];
    float Bv[16], Cv[16];
#pragma unroll
    for (int j = 0; j < 4; ++j) {
      *(float4*)&Bv[4 * j] = *(const float4*)(row + 4 * j);
      *(float4*)&Cv[4 * j] = *(const float4*)(row + 16 + 4 * j);
    }
    float dtx = dt * xv;
    float dA[16];
    if (fastp) {
      powladder_(__expf(A0 * dt), dA);
    } else {
#pragma unroll
      for (int s = 0; s < 16; ++s) dA[s] = __expf(Av[s] * dt);
    }
    float y0 = 0.f, y1 = 0.f, y2 = 0.f, y3 = 0.f;
#pragma unroll
    for (int s = 0; s < 16; s += 4) {
      h[s] = fmaf(dA[s], h[s], dtx * Bv[s]);       y0 = fmaf(h[s], Cv[s], y0);
      h[s + 1] = fmaf(dA[s + 1], h[s + 1], dtx * Bv[s + 1]); y1 = fmaf(h[s + 1], Cv[s + 1], y1);
      h[s + 2] = fmaf(dA[s + 2], h[s + 2], dtx * Bv[s + 2]); y2 = fmaf(h[s + 2], Cv[s + 2], y2);
      h[s + 3] = fmaf(dA[s + 3], h[s + 3], dtx * Bv[s + 3]); y3 = fmaf(h[s + 3], Cv[s + 3], y3);
    }
    float y = (y0 + y1) + (y2 + y3);
    float yf = fmaf(xv, Dp, y) * zv;
    pys[(size_t)t * DI] = (h16)yf;
    sum += yf;
  }
  atomicAdd(&SUMYF[i * DI + lane], sum);
}

// ---------------- K56: SE gates + gated combine (MFMA) + LN2 + proj (MFMA) ----
__global__ __launch_bounds__(256) void k56_comb_proj(
    const float* __restrict__ out_W, const float* __restrict__ skip_p,
    const float* __restrict__ se_W1, const float* __restrict__ se_W2,
    const float* __restrict__ SUMYF, const float* __restrict__ SUMXN,
    const h16* __restrict__ YS2, const float* __restrict__ gn,
    const float* __restrict__ bn, const h16* __restrict__ WH,
    const float* __restrict__ proj_b, const h16* __restrict__ XNH,
    float* __restrict__ out) {
  int bid = blockIdx.x;
  int b = bid >> 6, tile = bid & 63;
  int t0 = tile * 64;
  int tid = threadIdx.x;
  int w = __builtin_amdgcn_readfirstlane(tid >> 6);
  int lane = tid & 63;
  __shared__ __attribute__((aligned(16))) union {
    float xmS[64][132];
    _Float16 projH[64][136];   // one 64-row half of proj_W per pass
  } U;
  __shared__ __attribute__((aligned(16))) union {
    struct {
      _Float16 yH[64][72];
      _Float16 owH[32][72];
    } pre;
    _Float16 xmH[64][136];
  } V;
  __shared__ float gAll[4][64];
  __shared__ float gnS[128], bnS[128];
  float* catS = (float*)&V.pre.yH[0][0];   // 4*64 floats (within yH rows 0..7)
  float* seL = catS + 256;                 // 8 floats

  if (tid < 128) { gnS[tid] = gn[tid]; bnS[tid] = bn[tid]; }
  // owH: h16 vector copy from WH[7168..9216)
  for (int k = tid; k < 256; k += 256) {
    int r = k >> 3, c8 = (k & 7) * 8;
    *(f16x8*)&V.pre.owH[r][c8] = *(const f16x8*)&WH[7168 + r * 64 + c8];
  }
  // stage xm from XNH (h16 -> f32)
  const h16* xmh = XNH + (size_t)b * L_ * C_;
  for (int k = tid; k < 1024; k += 256) {
    int tt = k >> 4, c8 = (k & 15) * 8;
    f16x8 hv = *(const f16x8*)&xmh[(size_t)(t0 + tt) * C_ + c8];
#pragma unroll
    for (int j = 0; j < 8; ++j) U.xmS[tt][c8 + j] = (float)hv[j];
  }
  // ---- gates (folded k4): phase A -> catS
  {
    int ch = tid >> 6, j = tid & 63;
    float invL = 1.f / (float)L_;
    if (j < 32) {
      const float* sy = SUMYF + (b * 4 + ch) * DI;
      const float* ow = out_W + j * 64;
      float acc = 0.f;
#pragma unroll
      for (int dd = 0; dd < 64; ++dd) acc = fmaf(sy[dd], ow[dd], acc);
      catS[ch * 64 + j] = acc * invL;
    } else {
      catS[ch * 64 + j] = skip_p[0] * SUMXN[b * C_ + ch * DM + (j - 32)] * invL;
    }
  }
  __syncthreads();
  if (tid < 8) {
    int ch = tid >> 1, r = tid & 1;
    float acc = 0.f;
#pragma unroll
    for (int k = 0; k < 64; ++k) acc = fmaf(catS[ch * 64 + k], se_W1[r * 64 + k], acc);
    seL[tid] = fmaxf(acc, 0.f);
  }
  __syncthreads();
  {
    int ch = tid >> 6, j = tid & 63;
    gAll[ch][j] = sigmoidf_(fmaf(seL[ch * 2], se_W2[j * 2], seL[ch * 2 + 1] * se_W2[j * 2 + 1]));
  }
  __syncthreads();   // gates done; yH rows reusable (owH untouched)

  int rsel = lane & 15, ksel = (lane >> 4) * 8;
  float skip = skip_p[0];
  // per-channel gated combine: xm[tok][ch*32+o] = g1*M1 + g2*skip*xn
  for (int ch = 0; ch < 4; ++ch) {
    const h16* py = YS2 + ((size_t)(b * 4 + ch) * L_ + t0) * DI;
    for (int k = tid; k < 512; k += 256) {
      int tt = k >> 3, dblk = (k & 7) * 8;
      *(f16x8*)&V.pre.yH[tt][dblk] = *(const f16x8*)&py[(size_t)tt * DI + dblk];
    }
    __syncthreads();
    f16x8 a0 = *(const f16x8*)&V.pre.yH[w * 16 + rsel][ksel];
    f16x8 a1 = *(const f16x8*)&V.pre.yH[w * 16 + rsel][32 + ksel];
    int row0 = w * 16 + ((lane >> 4) << 2);
#pragma unroll
    for (int nt = 0; nt < 2; ++nt) {
      f16x8 b0 = *(const f16x8*)&V.pre.owH[nt * 16 + rsel][ksel];
      f16x8 b1 = *(const f16x8*)&V.pre.owH[nt * 16 + rsel][32 + ksel];
      f32x4 acc = {0.f, 0.f, 0.f, 0.f};
      acc = __builtin_amdgcn_mfma_f32_16x16x32_f16(a0, b0, acc, 0, 0, 0);
      acc = __builtin_amdgcn_mfma_f32_16x16x32_f16(a1, b1, acc, 0, 0, 0);
      int o = nt * 16 + rsel;
      float g1 = gAll[ch][o], g2s = gAll[ch][32 + o] * skip;
      int cc = ch * 32 + o;
#pragma unroll
      for (int r = 0; r < 4; ++r) {
        int tok = row0 + r;
        U.xmS[tok][cc] = g1 * acc[r] + g2s * U.xmS[tok][cc];
      }
    }
    __syncthreads();
  }

  // LN2 over xm rows
  {
    int tok = tid >> 2, q = tid & 3;
    float s = 0.f, qq = 0.f;
#pragma unroll
    for (int j = 0; j < 32; ++j) {
      float v = U.xmS[tok][4 * j + q];
      s += v; qq += v * v;
    }
    s = dpp_add_<0xB1>(s); qq = dpp_add_<0xB1>(qq);
    s = dpp_add_<0x4E>(s); qq = dpp_add_<0x4E>(qq);
    float m = s * (1.f / 128.f);
    float var = qq * (1.f / 128.f) - m * m;
    float rs = rsqrtf(var + 1e-5f);
#pragma unroll
    for (int j = 0; j < 32; ++j) {
      int c = 4 * j + q;
      float v = U.xmS[tok][c];
      U.xmS[tok][c] = (v - m) * rs * gnS[c] + bnS[c];
    }
  }
  __syncthreads();
  // convert LN output to h16 (xmH overlays dead yH/owH)
  for (int k = tid; k < 1024; k += 256) {
    int tt = k >> 4, cblk = (k & 15) * 8;
    float4 v0 = *(const float4*)&U.xmS[tt][cblk];
    float4 v1 = *(const float4*)&U.xmS[tt][cblk + 4];
    f16x8 hv;
    hv[0] = (_Float16)v0.x; hv[1] = (_Float16)v0.y;
    hv[2] = (_Float16)v0.z; hv[3] = (_Float16)v0.w;
    hv[4] = (_Float16)v1.x; hv[5] = (_Float16)v1.y;
    hv[6] = (_Float16)v1.z; hv[7] = (_Float16)v1.w;
    *(f16x8*)&V.xmH[tt][cblk] = hv;
  }
  __syncthreads();
  // proj MFMA in two 64-output-row passes (projH = h16 copy from WH)
  f16x8 af[4];
#pragma unroll
  for (int kc = 0; kc < 4; ++kc)
    af[kc] = *(const f16x8*)&V.xmH[w * 16 + rsel][kc * 32 + ksel];
  int row0 = w * 16 + ((lane >> 4) << 2);
#pragma unroll
  for (int half = 0; half < 2; ++half) {
    for (int k = tid; k < 1024; k += 256) {
      int o = k >> 4, cblk = (k & 15) * 8;
      *(f16x8*)&U.projH[o][cblk] =
          *(const f16x8*)&WH[9216 + (half * 64 + o) * 128 + cblk];
    }
    __syncthreads();
#pragma unroll
    for (int nt = 0; nt < 4; ++nt) {
      int ol = nt * 16 + rsel;
      int o = half * 64 + ol;
      float pb = proj_b[o];
      f32x4 acc = {pb, pb, pb, pb};
#pragma unroll
      for (int kc = 0; kc < 4; ++kc) {
        f16x8 bf = *(const f16x8*)&U.projH[ol][kc * 32 + ksel];
        acc = __builtin_amdgcn_mfma_f32_16x16x32_f16(af[kc], bf, acc, 0, 0, 0);
      }
      *(float4*)&out[((size_t)(b * OUT_ + o)) * L_ + t0 + row0] =
          make_float4(acc[0], acc[1], acc[2], acc[3]);
    }
    __syncthreads();
  }
}

extern "C" void kernel_launch(void* const* d_in, const int* in_sizes, int n_in,
                              void* d_out, int out_size, void* d_ws, size_t ws_size,
                              hipStream_t stream) {
  const float* x = (const float*)d_in[0];
  const float* norm_g = (const float*)d_in[1];
  const float* norm_b = (const float*)d_in[2];
  const float* proj_W = (const float*)d_in[3];
  const float* proj_b = (const float*)d_in[4];
  const float* skip = (const float*)d_in[5];
  const float* se_W1 = (const float*)d_in[6];
  const float* se_W2 = (const float*)d_in[7];
  const float* in_W = (const float*)d_in[8];
  const float* conv_W = (const float*)d_in[9];
  const float* conv_b = (const float*)d_in[10];
  const float* xproj_W = (const float*)d_in[11];
  const float* dt_W = (const float*)d_in[12];
  const float* dt_b = (const float*)d_in[13];
  const float* A_log = (const float*)d_in[14];
  const float* D_p = (const float*)d_in[15];
  const float* out_W = (const float*)d_in[16];
  float* out = (float*)d_out;

  // workspace (~70 MiB)
  float* SUMYF = (float*)d_ws;                      // NI*DI
  float* SUMXN = SUMYF + NI * DI;                   // B*C
  h16* Pp = (h16*)(SUMXN + B_ * C_);                // NI*NSEG*DI*DS h16 (seg-major)
  h16* Qp = Pp + (size_t)NI * DI * NSEG * DS;
  h16* YS2 = Qp + (size_t)NI * DI * NSEG * DS;      // NI*L*DI h16
  h16* SX2 = YS2 + (size_t)NI * L_ * DI;
  h16* SDT2 = SX2 + (size_t)NI * L_ * DI;
  h16* SB2 = SDT2 + (size_t)NI * L_ * DI;           // NI*L*DS h16
  h16* SC2 = SB2 + (size_t)NI * L_ * DS;
  h16* SZ2 = SC2 + (size_t)NI * L_ * DS;            // NI*L*DI h16 (silu(z))
  h16* XNH = SZ2 + (size_t)NI * L_ * DI;            // B*L*C h16
  h16* WH = XNH + (size_t)B_ * L_ * C_;             // 25600 h16 (all weights)
  float* AVT = (float*)(WH + 25600);                // 1024 f32 = -exp(A_log)

  hipMemsetAsync(SUMYF, 0, (size_t)(NI * DI + B_ * C_) * sizeof(float), stream);
  k1_ln<<<B_ * 64 + 104, 256, 0, stream>>>(x, norm_g, norm_b, in_W, xproj_W,
                                           out_W, proj_W, A_log, WH, AVT, XNH,
                                           SUMXN);
  k2_prep<<<NI * 64, 256, 0, stream>>>(WH, conv_W, conv_b, dt_W, dt_b, AVT,
                                       XNH, SX2, SDT2, SB2, SC2, SZ2, Pp, Qp);
  k3b_comb<<<512, 64, 0, stream>>>(Pp, Qp);
  k3c_scan<<<NI * 32, 256, 0, stream>>>(AVT, SDT2, SX2, SB2, SC2, SZ2, D_p,
                                        Pp, YS2, SUMYF);
  k56_comb_proj<<<B_ * 64, 256, 0, stream>>>(out_W, skip, se_W1, se_W2, SUMYF,
                                             SUMXN, YS2, norm_g, norm_b, WH,
                                             proj_b, XNH, out);
}